// Round 2
// baseline (393.625 us; speedup 1.0000x reference)
//
#include <hip/hip_runtime.h>
#include <math.h>

#define NKPT 17
#define BATCH 32

// One block per (b,n) keypoint. Block = C threads. Does:
//   1. gauss-pool 5x5 window from fm -> x0 (kf row), load ms row -> x1
//   2. h = [x0,x1] @ w1 + b1 ; LN ; relu -> r ; projected = r@w2+b2
//   3. q,k,v for both rows (fused over shared wqkv columns)
//   4. 2-token headwise-gated attention, o-mean
//   5. out = om @ wo + bo + projected
template<int C, int H, int W>
__global__ __launch_bounds__(C) void fused_level(
    const float* __restrict__ fm,    // (B,C,H,W)
    const float* __restrict__ kp,    // (B,N,2)
    const float* __restrict__ ms,    // (N,C)
    const float* __restrict__ w1,    // (2C,C)
    const float* __restrict__ b1,    // (C)
    const float* __restrict__ gvec,  // (C)
    const float* __restrict__ beta,  // (C)
    const float* __restrict__ w2,    // (C,C)
    const float* __restrict__ b2,    // (C)
    const float* __restrict__ wqkv,  // (C,3C)
    const float* __restrict__ bqkv,  // (3C)
    const float* __restrict__ wg,    // (C,8)
    const float* __restrict__ bg,    // (8)
    const float* __restrict__ wo,    // (C,C)
    const float* __restrict__ bo,    // (C)
    float* __restrict__ out)         // (B,N,C)
{
    constexpr int D = C / 8;           // head dim
    constexpr int NW = C / 64;         // waves per block

    __shared__ float x0[C], x1[C], hbuf[C];
    __shared__ float q0[C], k0[C], v0[C], q1[C], k1[C], v1[C];
    __shared__ float om[C];
    __shared__ float gw[25];
    __shared__ float gwsum_inv;
    __shared__ float redA[NW], redB[NW];
    __shared__ float stats[2];
    __shared__ float gates[2][8];
    __shared__ float att[2][2][8];

    const int j = threadIdx.x;
    const int blk = blockIdx.x;
    const int b = blk / NKPT, n = blk % NKPT;

    // ---- gaussian kernel weights (unnormalized; normalize via sum) ----
    if (j < 25) {
        int dy = j / 5 - 2, dx = j % 5 - 2;
        gw[j] = expf(-(float)(dy * dy + dx * dx) / 8.0f);
    }
    __syncthreads();
    if (j == 0) {
        float s = 0.f;
        #pragma unroll
        for (int t = 0; t < 25; ++t) s += gw[t];
        gwsum_inv = 1.0f / s;
    }

    // ---- keypoint -> clipped window indices ----
    float kx = kp[(b * NKPT + n) * 2 + 0];
    float ky = kp[(b * NKPT + n) * 2 + 1];
    float rx = kx * ((float)W / 192.0f);   // scale_x = W/ORIG_W
    float ry = ky * ((float)H / 256.0f);   // scale_y = H/ORIG_H
    int cx = (int)rintf(rx);               // round half-to-even, matches jnp.round
    int cy = (int)rintf(ry);
    int ix[5], iy[5];
    #pragma unroll
    for (int t = 0; t < 5; ++t) {
        ix[t] = min(max(cx + t - 2, 0), W - 1);
        iy[t] = min(max(cy + t - 2, 0), H - 1);
    }
    __syncthreads();  // gw + gwsum_inv ready

    // ---- gauss pool: thread j = channel j ----
    {
        const float* fmb = fm + ((size_t)b * C + j) * (H * W);
        float acc = 0.f;
        #pragma unroll
        for (int yy = 0; yy < 5; ++yy) {
            const float* row = fmb + iy[yy] * W;
            #pragma unroll
            for (int xx = 0; xx < 5; ++xx)
                acc += gw[yy * 5 + xx] * row[ix[xx]];
        }
        x0[j] = acc * gwsum_inv;
        x1[j] = ms[n * C + j];
    }
    __syncthreads();

    // ---- h = [x0,x1] @ w1 + b1 ----
    float hacc = b1[j];
    #pragma unroll 4
    for (int i = 0; i < C; ++i) hacc += x0[i] * w1[i * C + j];
    #pragma unroll 4
    for (int i = 0; i < C; ++i) hacc += x1[i] * w1[(C + i) * C + j];

    // ---- LayerNorm (population variance) ----
    {
        float s1 = hacc, s2 = hacc * hacc;
        #pragma unroll
        for (int o = 32; o > 0; o >>= 1) {
            s1 += __shfl_down(s1, o);
            s2 += __shfl_down(s2, o);
        }
        int lane = j & 63, wid = j >> 6;
        if (lane == 0) { redA[wid] = s1; redB[wid] = s2; }
        __syncthreads();
        if (j == 0) {
            float t1 = 0.f, t2 = 0.f;
            #pragma unroll
            for (int w = 0; w < NW; ++w) { t1 += redA[w]; t2 += redB[w]; }
            float m = t1 / (float)C;
            float v = t2 / (float)C - m * m;
            stats[0] = m;
            stats[1] = 1.0f / sqrtf(v + 1e-5f);
        }
        __syncthreads();
    }
    {
        float r = (hacc - stats[0]) * stats[1] * gvec[j] + beta[j];
        hbuf[j] = fmaxf(r, 0.f);
    }
    __syncthreads();

    // ---- projected = relu(h) @ w2 + b2 (kept in register) ----
    float pj = b2[j];
    #pragma unroll 4
    for (int i = 0; i < C; ++i) pj += hbuf[i] * w2[i * C + j];

    // ---- qkv for both rows, fused over shared weight loads ----
    {
        float aq0 = bqkv[j], ak0 = bqkv[C + j], av0 = bqkv[2 * C + j];
        float aq1 = aq0, ak1 = ak0, av1 = av0;
        #pragma unroll 2
        for (int i = 0; i < C; ++i) {
            float xi0 = x0[i], xi1 = x1[i];
            const float* wr = wqkv + (size_t)i * (3 * C);
            float wq = wr[j], wk = wr[C + j], wv = wr[2 * C + j];
            aq0 += xi0 * wq; aq1 += xi1 * wq;
            ak0 += xi0 * wk; ak1 += xi1 * wk;
            av0 += xi0 * wv; av1 += xi1 * wv;
        }
        q0[j] = aq0; k0[j] = ak0; v0[j] = av0;
        q1[j] = aq1; k1[j] = ak1; v1[j] = av1;
    }
    __syncthreads();

    // ---- headwise gates: 16 threads, each a full dot ----
    if (j < 16) {
        int s = j >> 3, hh = j & 7;
        const float* xs = s ? x1 : x0;
        float a = bg[hh];
        for (int i = 0; i < C; ++i) a += xs[i] * wg[i * 8 + hh];
        gates[s][hh] = 1.0f / (1.0f + expf(-a));
    }

    // ---- attention scores: 32 threads, each one (head, s, t) dot ----
    if (j < 32) {
        int hh = j >> 2, st = j & 3;
        const float* qs = (st & 2) ? q1 : q0;
        const float* kt = (st & 1) ? k1 : k0;
        float a = 0.f;
        for (int i = hh * D; i < (hh + 1) * D; ++i) a += qs[i] * kt[i];
        att[(st >> 1)][st & 1][hh] = a;
    }
    __syncthreads();

    // ---- softmax over t (scaled), 16 threads ----
    if (j < 16) {
        int s = j >> 3, hh = j & 7;
        const float inv = 1.0f / sqrtf((float)D);
        float a0 = att[s][0][hh] * inv, a1 = att[s][1][hh] * inv;
        float mx = fmaxf(a0, a1);
        float e0 = expf(a0 - mx), e1 = expf(a1 - mx);
        float den = e0 + e1;
        att[s][0][hh] = e0 / den;
        att[s][1][hh] = e1 / den;
    }
    __syncthreads();

    // ---- o = att @ v, gated, mean over the 2 tokens ----
    {
        int hh = j / D;
        float o0 = (att[0][0][hh] * v0[j] + att[0][1][hh] * v1[j]) * gates[0][hh];
        float o1 = (att[1][0][hh] * v0[j] + att[1][1][hh] * v1[j]) * gates[1][hh];
        om[j] = 0.5f * (o0 + o1);
    }
    __syncthreads();

    // ---- out = om @ wo + bo + projected ----
    float oacc = bo[j];
    #pragma unroll 4
    for (int i = 0; i < C; ++i) oacc += om[i] * wo[i * C + j];
    out[((size_t)b * NKPT + n) * C + j] = oacc + pj;
}

extern "C" void kernel_launch(void* const* d_in, const int* in_sizes, int n_in,
                              void* d_out, int out_size, void* d_ws, size_t ws_size,
                              hipStream_t stream) {
    (void)in_sizes; (void)n_in; (void)d_ws; (void)ws_size; (void)out_size;
    const float* fm0  = (const float*)d_in[0];   // (32,256,96,72)
    const float* fm1  = (const float*)d_in[1];   // (32,512,48,36)
    const float* kp   = (const float*)d_in[2];   // (32,17,2)

    const float* ms0     = (const float*)d_in[3];
    const float* p0_w1   = (const float*)d_in[4];
    const float* p0_b1   = (const float*)d_in[5];
    const float* p0_g    = (const float*)d_in[6];
    const float* p0_beta = (const float*)d_in[7];
    const float* p0_w2   = (const float*)d_in[8];
    const float* p0_b2   = (const float*)d_in[9];
    const float* a0_wqkv = (const float*)d_in[10];
    const float* a0_bqkv = (const float*)d_in[11];
    const float* a0_wg   = (const float*)d_in[12];
    const float* a0_bg   = (const float*)d_in[13];
    const float* a0_wo   = (const float*)d_in[14];
    const float* a0_bo   = (const float*)d_in[15];

    const float* ms1     = (const float*)d_in[16];
    const float* p1_w1   = (const float*)d_in[17];
    const float* p1_b1   = (const float*)d_in[18];
    const float* p1_g    = (const float*)d_in[19];
    const float* p1_beta = (const float*)d_in[20];
    const float* p1_w2   = (const float*)d_in[21];
    const float* p1_b2   = (const float*)d_in[22];
    const float* a1_wqkv = (const float*)d_in[23];
    const float* a1_bqkv = (const float*)d_in[24];
    const float* a1_wg   = (const float*)d_in[25];
    const float* a1_bg   = (const float*)d_in[26];
    const float* a1_wo   = (const float*)d_in[27];
    const float* a1_bo   = (const float*)d_in[28];

    float* out0 = (float*)d_out;                          // (32,17,256)
    float* out1 = (float*)d_out + (size_t)BATCH * NKPT * 256;  // (32,17,512)

    const int nblk = BATCH * NKPT;  // 544

    fused_level<256, 96, 72><<<nblk, 256, 0, stream>>>(
        fm0, kp, ms0, p0_w1, p0_b1, p0_g, p0_beta, p0_w2, p0_b2,
        a0_wqkv, a0_bqkv, a0_wg, a0_bg, a0_wo, a0_bo, out0);

    fused_level<512, 48, 36><<<nblk, 512, 0, stream>>>(
        fm1, kp, ms1, p1_w1, p1_b1, p1_g, p1_beta, p1_w2, p1_b2,
        a1_wqkv, a1_bqkv, a1_wg, a1_bg, a1_wo, a1_bo, out1);
}

// Round 3
// 288.646 us; speedup vs baseline: 1.3637x; 1.3637x over previous
//
#include <hip/hip_runtime.h>
#include <math.h>

#define NKPT 17
#define BATCH 32

// One block per (n, group-of-4-batches). Block = C threads, thread j owns
// output column j for all G keypoints. Meta row (ms[n]) matvecs computed once.
// Activations stored transposed in LDS ([C][G]) so one ds_read_b128 feeds
// G FMAs per weight load.
template<int C, int H, int W, int G>
__global__ __launch_bounds__(C) void fused_level(
    const float* __restrict__ fm,    // (B,C,H,W)
    const float* __restrict__ kp,    // (B,N,2)
    const float* __restrict__ ms,    // (N,C)
    const float* __restrict__ w1,    // (2C,C)
    const float* __restrict__ b1,    // (C)
    const float* __restrict__ gvec,  // (C)
    const float* __restrict__ beta,  // (C)
    const float* __restrict__ w2,    // (C,C)
    const float* __restrict__ b2,    // (C)
    const float* __restrict__ wqkv,  // (C,3C)
    const float* __restrict__ bqkv,  // (3C)
    const float* __restrict__ wg,    // (C,8)
    const float* __restrict__ bg,    // (8)
    const float* __restrict__ wo,    // (C,C)
    const float* __restrict__ bo,    // (C)
    float* __restrict__ out)         // (B,N,C)
{
    static_assert(G == 4, "float4 paths assume G==4");
    constexpr int D = C / 8;           // head dim
    constexpr int NW = C / 64;         // waves per block

    __shared__ float x0T[C * G];       // [C][G] pooled features, transposed
    __shared__ float x1s[C];           // meta row
    __shared__ float hT[C * G];        // relu(LN(h)) transposed
    __shared__ float q0T[C * G], k0T[C * G], v0T[C * G];
    __shared__ float q1s[C], k1s[C], v1s[C];
    __shared__ float omT[C * G];
    __shared__ float gw[25];
    __shared__ float gwsum_inv;
    __shared__ float red[NW][G][2];
    __shared__ float stats[G][2];
    __shared__ float gatesS[G + 1][8]; // rows 0..G-1: kf-row gate per keypoint; row G: meta gate
    __shared__ float sc[G][3][8];      // (q0g.k0g, q0g.k1, q1.k0g)
    __shared__ float sc11[8];          // q1.k1 (shared)
    __shared__ float attS[G][2][2][8];

    const int j = threadIdx.x;
    const int blk = blockIdx.x;
    const int n = blk % NKPT;
    const int b0 = (blk / NKPT) * G;

    // ---- gaussian kernel weights ----
    if (j < 25) {
        int dy = j / 5 - 2, dx = j % 5 - 2;
        gw[j] = expf(-(float)(dy * dy + dx * dx) / 8.0f);
    }
    __syncthreads();
    if (j == 0) {
        float s = 0.f;
        #pragma unroll
        for (int t = 0; t < 25; ++t) s += gw[t];
        gwsum_inv = 1.0f / s;
    }
    __syncthreads();

    // ---- gauss pool for G keypoints; thread j = channel j ----
    {
        float pool[G];
        #pragma unroll
        for (int g = 0; g < G; ++g) {
            int bb = b0 + g;
            float kx = kp[(bb * NKPT + n) * 2 + 0];
            float ky = kp[(bb * NKPT + n) * 2 + 1];
            int cx = (int)rintf(kx * ((float)W / 192.0f));  // half-to-even, matches jnp.round
            int cy = (int)rintf(ky * ((float)H / 256.0f));
            const float* fmb = fm + ((size_t)bb * C + j) * (H * W);
            float acc = 0.f;
            #pragma unroll
            for (int yy = 0; yy < 5; ++yy) {
                int iyy = min(max(cy + yy - 2, 0), H - 1);
                const float* row = fmb + iyy * W;
                #pragma unroll
                for (int xx = 0; xx < 5; ++xx) {
                    int ixx = min(max(cx + xx - 2, 0), W - 1);
                    acc += gw[yy * 5 + xx] * row[ixx];
                }
            }
            pool[g] = acc * gwsum_inv;
        }
        *(float4*)&x0T[j * G] = make_float4(pool[0], pool[1], pool[2], pool[3]);
        x1s[j] = ms[n * C + j];
    }
    __syncthreads();

    // ---- h = [x0,x1] @ w1 + b1 ----
    float ha[G] = {0.f, 0.f, 0.f, 0.f};
    #pragma unroll 8
    for (int i = 0; i < C; ++i) {
        float w = w1[(size_t)i * C + j];
        float4 xv = *(const float4*)&x0T[i * G];
        ha[0] += xv.x * w; ha[1] += xv.y * w; ha[2] += xv.z * w; ha[3] += xv.w * w;
    }
    float hm = b1[j];
    #pragma unroll 8
    for (int i = 0; i < C; ++i) {
        hm += x1s[i] * w1[(size_t)(C + i) * C + j];
    }
    #pragma unroll
    for (int g = 0; g < G; ++g) ha[g] += hm;

    // ---- LayerNorm stats (population variance), G at once ----
    {
        float s1[G], s2[G];
        #pragma unroll
        for (int g = 0; g < G; ++g) { s1[g] = ha[g]; s2[g] = ha[g] * ha[g]; }
        #pragma unroll
        for (int o = 32; o > 0; o >>= 1) {
            #pragma unroll
            for (int g = 0; g < G; ++g) {
                s1[g] += __shfl_down(s1[g], o);
                s2[g] += __shfl_down(s2[g], o);
            }
        }
        int lane = j & 63, wid = j >> 6;
        if (lane == 0) {
            #pragma unroll
            for (int g = 0; g < G; ++g) { red[wid][g][0] = s1[g]; red[wid][g][1] = s2[g]; }
        }
        __syncthreads();
        if (j < G) {
            float t1 = 0.f, t2 = 0.f;
            #pragma unroll
            for (int w = 0; w < NW; ++w) { t1 += red[w][j][0]; t2 += red[w][j][1]; }
            float m = t1 / (float)C;
            float v = t2 / (float)C - m * m;
            stats[j][0] = m;
            stats[j][1] = 1.0f / sqrtf(v + 1e-5f);
        }
        __syncthreads();
    }

    // ---- relu(LN) -> hT ----
    {
        float gj = gvec[j], bj = beta[j];
        float hv[G];
        #pragma unroll
        for (int g = 0; g < G; ++g)
            hv[g] = fmaxf((ha[g] - stats[g][0]) * stats[g][1] * gj + bj, 0.f);
        *(float4*)&hT[j * G] = make_float4(hv[0], hv[1], hv[2], hv[3]);
    }
    __syncthreads();

    // ---- projected = relu(h) @ w2 + b2 (registers, added at the end) ----
    float pj[G] = {0.f, 0.f, 0.f, 0.f};
    #pragma unroll 8
    for (int i = 0; i < C; ++i) {
        float w = w2[(size_t)i * C + j];
        float4 hv = *(const float4*)&hT[i * G];
        pj[0] += hv.x * w; pj[1] += hv.y * w; pj[2] += hv.z * w; pj[3] += hv.w * w;
    }
    {
        float b2j = b2[j];
        #pragma unroll
        for (int g = 0; g < G; ++g) pj[g] += b2j;
    }

    // ---- qkv: G kf rows + 1 shared meta row, fused over weight loads ----
    {
        float aq[G + 1] = {0,0,0,0,0}, ak[G + 1] = {0,0,0,0,0}, av[G + 1] = {0,0,0,0,0};
        #pragma unroll 8
        for (int i = 0; i < C; ++i) {
            const float* wr = wqkv + (size_t)i * (3 * C) + j;
            float wq = wr[0], wk = wr[C], wv = wr[2 * C];
            float4 xv = *(const float4*)&x0T[i * G];
            float x1i = x1s[i];
            aq[0] += xv.x * wq; aq[1] += xv.y * wq; aq[2] += xv.z * wq; aq[3] += xv.w * wq; aq[4] += x1i * wq;
            ak[0] += xv.x * wk; ak[1] += xv.y * wk; ak[2] += xv.z * wk; ak[3] += xv.w * wk; ak[4] += x1i * wk;
            av[0] += xv.x * wv; av[1] += xv.y * wv; av[2] += xv.z * wv; av[3] += xv.w * wv; av[4] += x1i * wv;
        }
        float bq = bqkv[j], bk = bqkv[C + j], bv = bqkv[2 * C + j];
        *(float4*)&q0T[j * G] = make_float4(aq[0] + bq, aq[1] + bq, aq[2] + bq, aq[3] + bq);
        *(float4*)&k0T[j * G] = make_float4(ak[0] + bk, ak[1] + bk, ak[2] + bk, ak[3] + bk);
        *(float4*)&v0T[j * G] = make_float4(av[0] + bv, av[1] + bv, av[2] + bv, av[3] + bv);
        q1s[j] = aq[4] + bq; k1s[j] = ak[4] + bk; v1s[j] = av[4] + bv;
    }
    __syncthreads();

    // ---- gates (threads 128..167) and attention scores (threads 0..103), parallel waves ----
    if (j >= 128 && j < 128 + (G + 1) * 8) {
        int t = j - 128, r = t >> 3, h = t & 7;
        float a = bg[h];
        for (int i = 0; i < C; ++i) {
            float xv = (r < G) ? x0T[i * G + r] : x1s[i];
            a += xv * wg[i * 8 + h];
        }
        gatesS[r][h] = 1.0f / (1.0f + expf(-a));
    }
    if (j < G * 24) {
        int g = j / 24, rem = j % 24, p = rem >> 3, h = rem & 7;
        const float* qb = (p == 2) ? q1s : (q0T + g);
        const int qs_ = (p == 2) ? 1 : G;
        const float* kb = (p == 1) ? k1s : (k0T + g);
        const int ks_ = (p == 1) ? 1 : G;
        float a = 0.f;
        for (int i = h * D; i < (h + 1) * D; ++i) a += qb[i * qs_] * kb[i * ks_];
        sc[g][p][h] = a;
    } else if (j < G * 24 + 8) {
        int h = j - G * 24;
        float a = 0.f;
        for (int i = h * D; i < (h + 1) * D; ++i) a += q1s[i] * k1s[i];
        sc11[h] = a;
    }
    __syncthreads();

    // ---- softmax over t per (g, s, head) ----
    if (j < G * 16) {
        int g = j >> 4, s = (j >> 3) & 1, h = j & 7;
        float a0 = s ? sc[g][2][h] : sc[g][0][h];
        float a1 = s ? sc11[h]     : sc[g][1][h];
        const float scale = 1.0f / sqrtf((float)D);
        a0 *= scale; a1 *= scale;
        float mx = fmaxf(a0, a1);
        float e0 = expf(a0 - mx), e1 = expf(a1 - mx);
        float inv = 1.0f / (e0 + e1);
        attS[g][s][0][h] = e0 * inv;
        attS[g][s][1][h] = e1 * inv;
    }
    __syncthreads();

    // ---- o = att @ v, gated, mean over the 2 tokens ----
    {
        int h = j / D;
        float4 vv = *(const float4*)&v0T[j * G];
        float v1j = v1s[j];
        float vg[G] = {vv.x, vv.y, vv.z, vv.w};
        float om_[G];
        float gmeta = gatesS[G][0 * 8 + 0]; // placeholder to keep layout clear (overwritten below)
        (void)gmeta;
        #pragma unroll
        for (int g = 0; g < G; ++g) {
            float o0 = (attS[g][0][0][h] * vg[g] + attS[g][0][1][h] * v1j) * gatesS[g][h];
            float o1 = (attS[g][1][0][h] * vg[g] + attS[g][1][1][h] * v1j) * gatesS[G][h];
            om_[g] = 0.5f * (o0 + o1);
        }
        *(float4*)&omT[j * G] = make_float4(om_[0], om_[1], om_[2], om_[3]);
    }
    __syncthreads();

    // ---- out = om @ wo + bo + projected ----
    {
        float oa[G] = {0.f, 0.f, 0.f, 0.f};
        #pragma unroll 8
        for (int i = 0; i < C; ++i) {
            float w = wo[(size_t)i * C + j];
            float4 ov = *(const float4*)&omT[i * G];
            oa[0] += ov.x * w; oa[1] += ov.y * w; oa[2] += ov.z * w; oa[3] += ov.w * w;
        }
        float boj = bo[j];
        #pragma unroll
        for (int g = 0; g < G; ++g)
            out[((size_t)(b0 + g) * NKPT + n) * C + j] = oa[g] + boj + pj[g];
    }
}

extern "C" void kernel_launch(void* const* d_in, const int* in_sizes, int n_in,
                              void* d_out, int out_size, void* d_ws, size_t ws_size,
                              hipStream_t stream) {
    (void)in_sizes; (void)n_in; (void)d_ws; (void)ws_size; (void)out_size;
    const float* fm0  = (const float*)d_in[0];   // (32,256,96,72)
    const float* fm1  = (const float*)d_in[1];   // (32,512,48,36)
    const float* kp   = (const float*)d_in[2];   // (32,17,2)

    const float* ms0     = (const float*)d_in[3];
    const float* p0_w1   = (const float*)d_in[4];
    const float* p0_b1   = (const float*)d_in[5];
    const float* p0_g    = (const float*)d_in[6];
    const float* p0_beta = (const float*)d_in[7];
    const float* p0_w2   = (const float*)d_in[8];
    const float* p0_b2   = (const float*)d_in[9];
    const float* a0_wqkv = (const float*)d_in[10];
    const float* a0_bqkv = (const float*)d_in[11];
    const float* a0_wg   = (const float*)d_in[12];
    const float* a0_bg   = (const float*)d_in[13];
    const float* a0_wo   = (const float*)d_in[14];
    const float* a0_bo   = (const float*)d_in[15];

    const float* ms1     = (const float*)d_in[16];
    const float* p1_w1   = (const float*)d_in[17];
    const float* p1_b1   = (const float*)d_in[18];
    const float* p1_g    = (const float*)d_in[19];
    const float* p1_beta = (const float*)d_in[20];
    const float* p1_w2   = (const float*)d_in[21];
    const float* p1_b2   = (const float*)d_in[22];
    const float* a1_wqkv = (const float*)d_in[23];
    const float* a1_bqkv = (const float*)d_in[24];
    const float* a1_wg   = (const float*)d_in[25];
    const float* a1_bg   = (const float*)d_in[26];
    const float* a1_wo   = (const float*)d_in[27];
    const float* a1_bo   = (const float*)d_in[28];

    float* out0 = (float*)d_out;                               // (32,17,256)
    float* out1 = (float*)d_out + (size_t)BATCH * NKPT * 256;  // (32,17,512)

    constexpr int G = 4;
    const int nblk = NKPT * (BATCH / G);  // 136

    fused_level<256, 96, 72, G><<<nblk, 256, 0, stream>>>(
        fm0, kp, ms0, p0_w1, p0_b1, p0_g, p0_beta, p0_w2, p0_b2,
        a0_wqkv, a0_bqkv, a0_wg, a0_bg, a0_wo, a0_bo, out0);

    fused_level<512, 48, 36, G><<<nblk, 512, 0, stream>>>(
        fm1, kp, ms1, p1_w1, p1_b1, p1_g, p1_beta, p1_w2, p1_b2,
        a1_wqkv, a1_bqkv, a1_wg, a1_bg, a1_wo, a1_bo, out1);
}

// Round 4
// 162.430 us; speedup vs baseline: 2.4234x; 1.7771x over previous
//
#include <hip/hip_runtime.h>
#include <math.h>

#define NKPT 17
#define BATCH 32
#define NT 512       // threads per block
#define GSZ 4        // keypoints (batches) per block

// LDS layout. All activation arrays are [G][C] so writes/reads are contiguous.
// hT is reused as `om` after w2 consumes it.
template<int C, int G>
struct Smem {
    float x0[G][C];          // pooled features
    float x1[C];             // meta row (ms[n])
    float hT[G][C];          // pre/post-LN hidden; later reused as om
    float q0[G][C];
    float k0[G][C];
    float v0[G][C];
    float q1[C], k1[C], v1[C];
    float4 scratch[NT];      // split-K reduction buffer
    float gw[25];
    float gwsum_inv;
    float stats[G][2];       // mean, rstd per keypoint
    float gates[G + 1][8];   // G kf gates + meta gate
    float sc[G][3][8];       // q0.k0, q0.k1, q1.k0
    float sc11[8];           // q1.k1
    float att[G][2][2][8];
};

__device__ inline void fma4(float4& a, float x, const float4& w) {
    a.x += x * w.x; a.y += x * w.y; a.z += x * w.z; a.w += x * w.w;
}
__device__ inline float4 add4(const float4& a, const float4& b) {
    return make_float4(a.x + b.x, a.y + b.y, a.z + b.z, a.w + b.w);
}

// Combine per-segment partial float4s. Valid result only for t < C/4.
template<int C, int G>
__device__ inline float4 block_reduce4(Smem<C, G>& S_, float4 v, int t) {
    constexpr int J4 = C / 4;
    constexpr int NSEG = NT / J4;
    __syncthreads();                 // protect previous pass's readers
    S_.scratch[t] = v;
    __syncthreads();
    float4 r = make_float4(0.f, 0.f, 0.f, 0.f);
    if (t < J4) {
        #pragma unroll
        for (int s = 0; s < NSEG; ++s) r = add4(r, S_.scratch[s * J4 + t]);
    }
    return r;
}

template<int C, int H, int W, int G>
__device__ void fused_impl(char* raw, int blk,
    const float* __restrict__ fm,   const float* __restrict__ kp,
    const float* __restrict__ ms,
    const float* __restrict__ w1,   const float* __restrict__ b1,
    const float* __restrict__ gvec, const float* __restrict__ beta,
    const float* __restrict__ w2,   const float* __restrict__ b2,
    const float* __restrict__ wqkv, const float* __restrict__ bqkv,
    const float* __restrict__ wg,   const float* __restrict__ bg,
    const float* __restrict__ wo,   const float* __restrict__ bo,
    float* __restrict__ out)
{
    auto& S_ = *reinterpret_cast<Smem<C, G>*>(raw);
    constexpr int D    = C / 8;       // head dim
    constexpr int J4   = C / 4;       // column groups of 4
    constexpr int NSEG = NT / J4;     // K-split segments
    constexpr int LSEG = C / NSEG;    // segment length
    const int t  = threadIdx.x;
    const int n  = blk % NKPT;
    const int b0 = (blk / NKPT) * G;
    const int j4 = t % J4;
    const int sseg = t / J4;
    const int cb = 4 * j4;            // column base (owns cb..cb+3)
    const int i0 = sseg * LSEG;       // K-segment start

    // ---- gaussian window weights ----
    if (t < 25) {
        int dy = t / 5 - 2, dx = t % 5 - 2;
        S_.gw[t] = expf(-(float)(dy * dy + dx * dx) / 8.0f);
    }
    __syncthreads();
    if (t == 0) {
        float s = 0.f;
        #pragma unroll
        for (int u = 0; u < 25; ++u) s += S_.gw[u];
        S_.gwsum_inv = 1.0f / s;
    }
    if (t < C) S_.x1[t] = ms[n * C + t];
    __syncthreads();

    // ---- gauss pool: thread -> (channel, subset of keypoints) ----
    {
        constexpr int GPT = (C * G) / NT;   // keypoints per thread
        int c  = t % C;
        int g0 = (t / C) * GPT;
        for (int gg = 0; gg < GPT; ++gg) {
            int g = g0 + gg;
            int bb = b0 + g;
            float kx = kp[(bb * NKPT + n) * 2 + 0];
            float ky = kp[(bb * NKPT + n) * 2 + 1];
            int cx = (int)rintf(kx * ((float)W / 192.0f));  // half-to-even == jnp.round
            int cy = (int)rintf(ky * ((float)H / 256.0f));
            const float* fmb = fm + ((size_t)bb * C + c) * (H * W);
            float acc = 0.f;
            #pragma unroll
            for (int yy = 0; yy < 5; ++yy) {
                int iy = min(max(cy + yy - 2, 0), H - 1);
                const float* row = fmb + iy * W;
                #pragma unroll
                for (int xx = 0; xx < 5; ++xx) {
                    int ixx = min(max(cx + xx - 2, 0), W - 1);
                    acc += S_.gw[yy * 5 + xx] * row[ixx];
                }
            }
            S_.x0[g][c] = acc * S_.gwsum_inv;
        }
    }
    __syncthreads();

    float4 pj[G];   // projected (w2) results; valid on t < J4 only

    // ---- h = [x0;x1] @ w1 (+b1), split-K, float4 columns ----
    {
        float4 a[G + 1];
        #pragma unroll
        for (int r = 0; r <= G; ++r) a[r] = make_float4(0.f, 0.f, 0.f, 0.f);
        const float* wA = w1 + (size_t)i0 * C + cb;        // kf rows
        const float* wB = w1 + (size_t)(C + i0) * C + cb;  // meta rows
        #pragma unroll 4
        for (int i = 0; i < LSEG; ++i) {
            float4 wa = *(const float4*)(wA + (size_t)i * C);
            float4 wb = *(const float4*)(wB + (size_t)i * C);
            int ii = i0 + i;
            #pragma unroll
            for (int g = 0; g < G; ++g) fma4(a[g], S_.x0[g][ii], wa);
            fma4(a[G], S_.x1[ii], wb);
        }
        float4 mred = block_reduce4(S_, a[G], t);
        if (t < J4) mred = add4(mred, *(const float4*)(b1 + cb));
        #pragma unroll
        for (int g = 0; g < G; ++g) {
            float4 r = block_reduce4(S_, a[g], t);
            if (t < J4) *(float4*)&S_.hT[g][cb] = add4(r, mred);
        }
    }
    __syncthreads();

    // ---- LN stats: one wave per keypoint ----
    {
        int wv = t >> 6, ln = t & 63;
        if (wv < G) {
            float s1 = 0.f, s2 = 0.f;
            for (int c = ln; c < C; c += 64) { float h = S_.hT[wv][c]; s1 += h; s2 += h * h; }
            #pragma unroll
            for (int o = 32; o > 0; o >>= 1) { s1 += __shfl_down(s1, o); s2 += __shfl_down(s2, o); }
            if (ln == 0) {
                float m = s1 / (float)C;
                float v = s2 / (float)C - m * m;
                S_.stats[wv][0] = m;
                S_.stats[wv][1] = 1.0f / sqrtf(v + 1e-5f);
            }
        }
    }
    __syncthreads();
    // ---- normalize + relu in place ----
    for (int idx = t; idx < G * C; idx += NT) {
        int g = idx / C, c = idx % C;
        float h = (&S_.hT[0][0])[idx];
        h = (h - S_.stats[g][0]) * S_.stats[g][1] * gvec[c] + beta[c];
        (&S_.hT[0][0])[idx] = fmaxf(h, 0.f);
    }
    __syncthreads();

    // ---- projected = relu(h) @ w2 + b2 ----
    {
        float4 a[G];
        #pragma unroll
        for (int g = 0; g < G; ++g) a[g] = make_float4(0.f, 0.f, 0.f, 0.f);
        const float* wp = w2 + (size_t)i0 * C + cb;
        #pragma unroll 4
        for (int i = 0; i < LSEG; ++i) {
            float4 w = *(const float4*)(wp + (size_t)i * C);
            int ii = i0 + i;
            #pragma unroll
            for (int g = 0; g < G; ++g) fma4(a[g], S_.hT[g][ii], w);
        }
        float4 b2v = make_float4(0.f, 0.f, 0.f, 0.f);
        if (t < J4) b2v = *(const float4*)(b2 + cb);
        #pragma unroll
        for (int g = 0; g < G; ++g) {
            float4 r = block_reduce4(S_, a[g], t);
            pj[g] = add4(r, b2v);
        }
    }

    // ---- q, k, v: three passes, each G kf rows + 1 meta row ----
    for (int qq = 0; qq < 3; ++qq) {
        float4 a[G + 1];
        #pragma unroll
        for (int r = 0; r <= G; ++r) a[r] = make_float4(0.f, 0.f, 0.f, 0.f);
        const float* wp = wqkv + (size_t)i0 * (3 * C) + qq * C + cb;
        #pragma unroll 4
        for (int i = 0; i < LSEG; ++i) {
            float4 w = *(const float4*)(wp + (size_t)i * (3 * C));
            int ii = i0 + i;
            #pragma unroll
            for (int g = 0; g < G; ++g) fma4(a[g], S_.x0[g][ii], w);
            fma4(a[G], S_.x1[ii], w);
        }
        float (*dst0)[C] = (qq == 0) ? S_.q0 : (qq == 1) ? S_.k0 : S_.v0;
        float* dst1      = (qq == 0) ? S_.q1 : (qq == 1) ? S_.k1 : S_.v1;
        float4 mred = block_reduce4(S_, a[G], t);
        float4 bv = make_float4(0.f, 0.f, 0.f, 0.f);
        if (t < J4) {
            bv = *(const float4*)(bqkv + qq * C + cb);
            *(float4*)&dst1[cb] = add4(mred, bv);
        }
        #pragma unroll
        for (int g = 0; g < G; ++g) {
            float4 r = block_reduce4(S_, a[g], t);
            if (t < J4) *(float4*)&dst0[g][cb] = add4(r, bv);
        }
    }
    __syncthreads();

    // ---- attention scores (96+8 threads) and gates (40 threads) ----
    if (t < G * 24) {
        int g = t / 24, rem = t % 24, p = rem / 8, h = rem % 8;
        const float* qv = (p == 2) ? S_.q1 : S_.q0[g];
        const float* kv = (p == 1) ? S_.k1 : S_.k0[g];
        float a = 0.f;
        for (int i = h * D; i < h * D + D; ++i) a += qv[i] * kv[i];
        S_.sc[g][p][h] = a;
    } else if (t < G * 24 + 8) {
        int h = t - G * 24;
        float a = 0.f;
        for (int i = h * D; i < h * D + D; ++i) a += S_.q1[i] * S_.k1[i];
        S_.sc11[h] = a;
    } else if (t < G * 24 + 8 + (G + 1) * 8) {
        int u = t - (G * 24 + 8);
        int r = u / 8, h = u % 8;
        const float* xv = (r < G) ? S_.x0[r] : S_.x1;
        float a = bg[h];
        for (int i = 0; i < C; ++i) a += xv[i] * wg[i * 8 + h];
        S_.gates[r][h] = 1.0f / (1.0f + expf(-a));
    }
    __syncthreads();

    // ---- 2-token softmax ----
    if (t < G * 16) {
        int g = t >> 4, s4 = (t >> 3) & 1, h = t & 7;
        float a0 = s4 ? S_.sc[g][2][h] : S_.sc[g][0][h];
        float a1 = s4 ? S_.sc11[h]     : S_.sc[g][1][h];
        const float scl = 1.0f / sqrtf((float)D);
        a0 *= scl; a1 *= scl;
        float mx = fmaxf(a0, a1);
        float e0 = expf(a0 - mx), e1 = expf(a1 - mx);
        float inv = 1.0f / (e0 + e1);
        S_.att[g][s4][0][h] = e0 * inv;
        S_.att[g][s4][1][h] = e1 * inv;
    }
    __syncthreads();

    // ---- o = att@v, gated, token-mean -> om (reuses hT storage) ----
    float (*om)[C] = S_.hT;
    for (int c = t; c < C; c += NT) {
        int h = c / D;
        float v1c = S_.v1[c];
        #pragma unroll
        for (int g = 0; g < G; ++g) {
            float vg = S_.v0[g][c];
            float o0 = (S_.att[g][0][0][h] * vg + S_.att[g][0][1][h] * v1c) * S_.gates[g][h];
            float o1 = (S_.att[g][1][0][h] * vg + S_.att[g][1][1][h] * v1c) * S_.gates[G][h];
            om[g][c] = 0.5f * (o0 + o1);
        }
    }
    __syncthreads();

    // ---- out = om @ wo + bo + projected ----
    {
        float4 a[G];
        #pragma unroll
        for (int g = 0; g < G; ++g) a[g] = make_float4(0.f, 0.f, 0.f, 0.f);
        const float* wp = wo + (size_t)i0 * C + cb;
        #pragma unroll 4
        for (int i = 0; i < LSEG; ++i) {
            float4 w = *(const float4*)(wp + (size_t)i * C);
            int ii = i0 + i;
            #pragma unroll
            for (int g = 0; g < G; ++g) fma4(a[g], om[g][ii], w);
        }
        float4 bov = make_float4(0.f, 0.f, 0.f, 0.f);
        if (t < J4) bov = *(const float4*)(bo + cb);
        #pragma unroll
        for (int g = 0; g < G; ++g) {
            float4 r = block_reduce4(S_, a[g], t);
            if (t < J4) {
                float4 o = add4(add4(r, bov), pj[g]);
                *(float4*)&out[(((size_t)(b0 + g) * NKPT) + n) * C + cb] = o;
            }
        }
    }
}

__global__ __launch_bounds__(NT, 4) void fused_all(
    const float* fm0, const float* fm1, const float* kp,
    const float* ms0, const float* p0_w1, const float* p0_b1, const float* p0_g,
    const float* p0_beta, const float* p0_w2, const float* p0_b2,
    const float* a0_wqkv, const float* a0_bqkv, const float* a0_wg,
    const float* a0_bg, const float* a0_wo, const float* a0_bo,
    const float* ms1, const float* p1_w1, const float* p1_b1, const float* p1_g,
    const float* p1_beta, const float* p1_w2, const float* p1_b2,
    const float* a1_wqkv, const float* a1_bqkv, const float* a1_wg,
    const float* a1_bg, const float* a1_wo, const float* a1_bo,
    float* out0, float* out1)
{
    __shared__ __align__(16) char raw[sizeof(Smem<512, GSZ>)];
    const int nblk1 = NKPT * (BATCH / GSZ);   // 136, level-1 first (long pole)
    int blk = blockIdx.x;
    if (blk < nblk1) {
        fused_impl<512, 48, 36, GSZ>(raw, blk, fm1, kp, ms1,
            p1_w1, p1_b1, p1_g, p1_beta, p1_w2, p1_b2,
            a1_wqkv, a1_bqkv, a1_wg, a1_bg, a1_wo, a1_bo, out1);
    } else {
        fused_impl<256, 96, 72, GSZ>(raw, blk - nblk1, fm0, kp, ms0,
            p0_w1, p0_b1, p0_g, p0_beta, p0_w2, p0_b2,
            a0_wqkv, a0_bqkv, a0_wg, a0_bg, a0_wo, a0_bo, out0);
    }
}

extern "C" void kernel_launch(void* const* d_in, const int* in_sizes, int n_in,
                              void* d_out, int out_size, void* d_ws, size_t ws_size,
                              hipStream_t stream) {
    (void)in_sizes; (void)n_in; (void)d_ws; (void)ws_size; (void)out_size;
    const float* fm0  = (const float*)d_in[0];   // (32,256,96,72)
    const float* fm1  = (const float*)d_in[1];   // (32,512,48,36)
    const float* kp   = (const float*)d_in[2];   // (32,17,2)

    const float* ms0     = (const float*)d_in[3];
    const float* p0_w1   = (const float*)d_in[4];
    const float* p0_b1   = (const float*)d_in[5];
    const float* p0_g    = (const float*)d_in[6];
    const float* p0_beta = (const float*)d_in[7];
    const float* p0_w2   = (const float*)d_in[8];
    const float* p0_b2   = (const float*)d_in[9];
    const float* a0_wqkv = (const float*)d_in[10];
    const float* a0_bqkv = (const float*)d_in[11];
    const float* a0_wg   = (const float*)d_in[12];
    const float* a0_bg   = (const float*)d_in[13];
    const float* a0_wo   = (const float*)d_in[14];
    const float* a0_bo   = (const float*)d_in[15];

    const float* ms1     = (const float*)d_in[16];
    const float* p1_w1   = (const float*)d_in[17];
    const float* p1_b1   = (const float*)d_in[18];
    const float* p1_g    = (const float*)d_in[19];
    const float* p1_beta = (const float*)d_in[20];
    const float* p1_w2   = (const float*)d_in[21];
    const float* p1_b2   = (const float*)d_in[22];
    const float* a1_wqkv = (const float*)d_in[23];
    const float* a1_bqkv = (const float*)d_in[24];
    const float* a1_wg   = (const float*)d_in[25];
    const float* a1_bg   = (const float*)d_in[26];
    const float* a1_wo   = (const float*)d_in[27];
    const float* a1_bo   = (const float*)d_in[28];

    float* out0 = (float*)d_out;                               // (32,17,256)
    float* out1 = (float*)d_out + (size_t)BATCH * NKPT * 256;  // (32,17,512)

    const int nblk = 2 * NKPT * (BATCH / GSZ);  // 272

    fused_all<<<nblk, NT, 0, stream>>>(
        fm0, fm1, kp,
        ms0, p0_w1, p0_b1, p0_g, p0_beta, p0_w2, p0_b2,
        a0_wqkv, a0_bqkv, a0_wg, a0_bg, a0_wo, a0_bo,
        ms1, p1_w1, p1_b1, p1_g, p1_beta, p1_w2, p1_b2,
        a1_wqkv, a1_bqkv, a1_wg, a1_bg, a1_wo, a1_bo,
        out0, out1);
}

// Round 5
// 131.958 us; speedup vs baseline: 2.9829x; 1.2309x over previous
//
#include <hip/hip_runtime.h>
#include <math.h>

#define NKPT 17
#define BATCH 32
#define MROW 544          // BATCH*NKPT
#define MPAD 576          // 9*64

typedef unsigned short u16;
typedef _Float16 half8 __attribute__((ext_vector_type(8)));
typedef float f32x4 __attribute__((ext_vector_type(4)));

__device__ __forceinline__ u16 f2h(float f) {
    _Float16 h = (_Float16)f;
    u16 u; __builtin_memcpy(&u, &h, 2); return u;
}

// ---------------------------------------------------------------- GEMM ----
// BM=64, BN=128, BK=64, 256 threads (4 waves, each 32x64 of C).
// A: f32 [Mpad][lda], converted to fp16 while staging. BT: fp16 [N][K].
struct GD {
    const float* A; const u16* BT; const float* bias; const float* add;
    float* dst; int lda, ldd, K, N, mstore, ntiles;
};
struct GP { GD d[4]; int blk0[5]; int nd; };

__device__ void gemm_block(const GD& g, int local, char* smem)
{
    u16 (*sA)[72] = reinterpret_cast<u16(*)[72]>(smem);                 // [64][72]
    u16 (*sB)[72] = reinterpret_cast<u16(*)[72]>(smem + 64 * 72 * 2);   // [128][72]
    const int t = threadIdx.x;
    const int mt = local / g.ntiles, nt = local % g.ntiles;
    const int m0 = mt * 64, n0 = nt * 128;
    const int l = t & 63, w = t >> 6, wr = w >> 1, wc = w & 1;

    f32x4 acc[2][4];
    #pragma unroll
    for (int i = 0; i < 2; ++i)
        #pragma unroll
        for (int j = 0; j < 4; ++j) {
            f32x4 z = {0.f, 0.f, 0.f, 0.f};
            acc[i][j] = z;
        }

    const int ar = t >> 2, akq = (t & 3) << 4;   // A stage: row 0..63, k-chunk of 16
    const int bn = t >> 1, bkq = (t & 1) << 5;   // B stage: row 0..127, k-chunk of 32

    for (int k0 = 0; k0 < g.K; k0 += 64) {
        // stage A (f32 global -> fp16 LDS)
        {
            const float* ap = g.A + (size_t)(m0 + ar) * g.lda + k0 + akq;
            #pragma unroll
            for (int i = 0; i < 4; ++i) {
                float4 v = *(const float4*)(ap + 4 * i);
                ushort4 h4 = make_ushort4(f2h(v.x), f2h(v.y), f2h(v.z), f2h(v.w));
                *reinterpret_cast<ushort4*>(&sA[ar][akq + 4 * i]) = h4;
            }
        }
        // stage B (fp16 transposed weights -> LDS)
        {
            const u16* bp = g.BT + (size_t)(n0 + bn) * g.K + k0 + bkq;
            #pragma unroll
            for (int i = 0; i < 4; ++i)
                *reinterpret_cast<uint4*>(&sB[bn][bkq + 8 * i]) =
                    *reinterpret_cast<const uint4*>(bp + 8 * i);
        }
        __syncthreads();

        #pragma unroll
        for (int ks = 0; ks < 64; ks += 32) {
            const int koff = ks + (l >> 4) * 8;
            half8 af0 = *reinterpret_cast<const half8*>(&sA[wr * 32 + (l & 15)][koff]);
            half8 af1 = *reinterpret_cast<const half8*>(&sA[wr * 32 + 16 + (l & 15)][koff]);
            half8 bf[4];
            #pragma unroll
            for (int j = 0; j < 4; ++j)
                bf[j] = *reinterpret_cast<const half8*>(&sB[wc * 64 + j * 16 + (l & 15)][koff]);
            #pragma unroll
            for (int j = 0; j < 4; ++j) {
                acc[0][j] = __builtin_amdgcn_mfma_f32_16x16x32_f16(af0, bf[j], acc[0][j], 0, 0, 0);
                acc[1][j] = __builtin_amdgcn_mfma_f32_16x16x32_f16(af1, bf[j], acc[1][j], 0, 0, 0);
            }
        }
        __syncthreads();
    }

    // epilogue: D row=(l>>4)*4+reg, col=l&15 (verified layout)
    #pragma unroll
    for (int i = 0; i < 2; ++i) {
        #pragma unroll
        for (int j = 0; j < 4; ++j) {
            int col = n0 + wc * 64 + j * 16 + (l & 15);
            #pragma unroll
            for (int rr = 0; rr < 4; ++rr) {
                int m = m0 + wr * 32 + i * 16 + (l >> 4) * 4 + rr;
                if (m < g.mstore) {
                    float v = acc[i][j][rr];
                    if (g.bias) v += g.bias[col];
                    if (g.add)  v += g.add[(size_t)m * g.ldd + col];
                    g.dst[(size_t)m * g.ldd + col] = v;
                }
            }
        }
    }
}

__global__ __launch_bounds__(256) void gemm_multi(GP P)
{
    __shared__ char smem[64 * 72 * 2 + 128 * 72 * 2];
    int bid = blockIdx.x, i = 0;
    while (i + 1 < P.nd && bid >= P.blk0[i + 1]) ++i;
    gemm_block(P.d[i], bid - P.blk0[i], smem);
}

// ---------------------------------------------------------------- prep ----
struct TD { const float* src; u16* dst; int K, N, blk0; };
struct PrepP {
    const float *fm0, *fm1, *kp, *ms0, *ms1;
    float *A1_0, *A1_1;
    TD td[8];
};

template<int C, int H, int W>
__device__ void pool_row(int b, int n, const float* fm, const float* kp,
                         const float* ms, float* A1, float* sg)
{
    const int t = threadIdx.x;
    if (t < 25) {
        int dy = t / 5 - 2, dx = t % 5 - 2;
        sg[t] = expf(-(float)(dy * dy + dx * dx) / 8.0f);
    }
    __syncthreads();
    if (t == 0) {
        float s = 0.f;
        #pragma unroll
        for (int u2 = 0; u2 < 25; ++u2) s += sg[u2];
        sg[25] = 1.0f / s;
    }
    __syncthreads();
    float kx = kp[(b * NKPT + n) * 2 + 0];
    float ky = kp[(b * NKPT + n) * 2 + 1];
    int cx = (int)rintf(kx * ((float)W / 192.0f));   // RNE == jnp.round
    int cy = (int)rintf(ky * ((float)H / 256.0f));
    int ix[5], iy[5];
    #pragma unroll
    for (int q = 0; q < 5; ++q) {
        ix[q] = min(max(cx + q - 2, 0), W - 1);
        iy[q] = min(max(cy + q - 2, 0), H - 1);
    }
    const float inv = sg[25];
    float* row = A1 + (size_t)(b * NKPT + n) * (2 * C);
    for (int c = t; c < C; c += 256) {
        const float* fmb = fm + ((size_t)b * C + c) * (H * W);
        float acc = 0.f;
        #pragma unroll
        for (int yy = 0; yy < 5; ++yy) {
            const float* rr = fmb + iy[yy] * W;
            #pragma unroll
            for (int xx = 0; xx < 5; ++xx) acc += sg[yy * 5 + xx] * rr[ix[xx]];
        }
        row[c] = acc * inv;
        row[C + c] = ms[n * C + c];
    }
}

template<int C>
__device__ void meta_row(int n, const float* ms, float* A1)
{
    float* row = A1 + (size_t)(MROW + n) * (2 * C);
    for (int c = threadIdx.x; c < C; c += 256) { row[c] = ms[n * C + c]; row[C + c] = 0.f; }
}
template<int C>
__device__ void zero_row(int i, float* A1)
{
    float* row = A1 + (size_t)(MROW + NKPT + i) * (2 * C);
    for (int c = threadIdx.x; c < 2 * C; c += 256) row[c] = 0.f;
}

__device__ void wtrans_tile(const TD& d, int u, float* sT)  // sT: [64][65] f32
{
    const int ntx = d.N >> 6;
    const int tk = u / ntx, tn = u % ntx;
    const int k0 = tk << 6, n0 = tn << 6;
    const int t = threadIdx.x;
    {
        int r = t >> 2, cq = (t & 3) << 4;
        const float* sp = d.src + (size_t)(k0 + r) * d.N + n0 + cq;
        #pragma unroll
        for (int i = 0; i < 4; ++i) {
            float4 v = *(const float4*)(sp + 4 * i);
            sT[r * 65 + cq + 4 * i + 0] = v.x;
            sT[r * 65 + cq + 4 * i + 1] = v.y;
            sT[r * 65 + cq + 4 * i + 2] = v.z;
            sT[r * 65 + cq + 4 * i + 3] = v.w;
        }
    }
    __syncthreads();
    {
        int nn = t >> 2, kq = (t & 3) << 4;
        u16 hv[16] __attribute__((aligned(16)));
        #pragma unroll
        for (int i = 0; i < 16; ++i) hv[i] = f2h(sT[(kq + i) * 65 + nn]);
        u16* dp = d.dst + (size_t)(n0 + nn) * d.K + k0 + kq;
        *reinterpret_cast<uint4*>(dp) = *reinterpret_cast<uint4*>(&hv[0]);
        *reinterpret_cast<uint4*>(dp + 8) = *reinterpret_cast<uint4*>(&hv[8]);
    }
}

__global__ __launch_bounds__(256) void prep(PrepP P)
{
    __shared__ float ps[64 * 65];
    int bid = blockIdx.x;
    if (bid < 1088) {
        if (bid < 544) { int r = bid;       pool_row<512, 48, 36>(r / NKPT, r % NKPT, P.fm1, P.kp, P.ms1, P.A1_1, ps); }
        else           { int r = bid - 544; pool_row<256, 96, 72>(r / NKPT, r % NKPT, P.fm0, P.kp, P.ms0, P.A1_0, ps); }
    } else if (bid < 1122) {
        int u = bid - 1088;
        if (u < NKPT) meta_row<512>(u, P.ms1, P.A1_1);
        else          meta_row<256>(u - NKPT, P.ms0, P.A1_0);
    } else if (bid < 1152) {
        int u = bid - 1122;
        if (u < 15) zero_row<512>(u, P.A1_1);
        else        zero_row<256>(u - 15, P.A1_0);
    } else {
        int u = bid - 1152, i = 0;
        while (i + 1 < 8 && u >= P.td[i + 1].blk0) ++i;
        wtrans_tile(P.td[i], u - P.td[i].blk0, ps);
    }
}

// ------------------------------------------------------------- LN+relu ----
struct LnP { float *h1, *h0; const float *g1, *be1, *g0, *be0; };
__global__ __launch_bounds__(256) void lnrelu(LnP P)
{
    __shared__ float red[8];
    __shared__ float st[2];
    int bid = blockIdx.x;
    int lvl1 = bid < 544;
    int r = lvl1 ? bid : bid - 544;
    int C = lvl1 ? 512 : 256;
    float* h = (lvl1 ? P.h1 : P.h0) + (size_t)r * C;
    const float* gg = lvl1 ? P.g1 : P.g0;
    const float* bb = lvl1 ? P.be1 : P.be0;
    int t = threadIdx.x;
    int nc = C >> 8;
    float v[2] = {0.f, 0.f};
    float s1 = 0.f, s2 = 0.f;
    for (int i = 0; i < nc; ++i) { float x = h[t + (i << 8)]; v[i] = x; s1 += x; s2 += x * x; }
    #pragma unroll
    for (int o = 32; o > 0; o >>= 1) { s1 += __shfl_down(s1, o); s2 += __shfl_down(s2, o); }
    int lane = t & 63, wv = t >> 6;
    if (lane == 0) { red[wv * 2] = s1; red[wv * 2 + 1] = s2; }
    __syncthreads();
    if (t == 0) {
        float a = 0.f, b = 0.f;
        #pragma unroll
        for (int q = 0; q < 4; ++q) { a += red[q * 2]; b += red[q * 2 + 1]; }
        float m = a / (float)C;
        float var = b / (float)C - m * m;
        st[0] = m; st[1] = 1.0f / sqrtf(var + 1e-5f);
    }
    __syncthreads();
    float m = st[0], rs = st[1];
    for (int i = 0; i < nc; ++i) {
        int c = t + (i << 8);
        float x = (v[i] - m) * rs * gg[c] + bb[c];
        h[c] = fmaxf(x, 0.f);
    }
}

// ------------------------------------------------- mid: w2-GEMM + attn ----
template<int C>
__device__ void attn_row(int r, const float* qkv, const float* A1, int lda,
                         const float* wg, const float* bg, float* om, float* sred)
{
    constexpr int D = C / 8;
    constexpr int TC = 3 * C;
    const int t = threadIdx.x;
    const int n = r % NKPT;
    const float* row  = qkv + (size_t)r * TC;
    const float* mrow = qkv + (size_t)(MROW + n) * TC;
    // sred: [0..31] raw scores (p*8+h, p=s*2+tt), [32..47] gates, [48..55] cv0, [56..63] cv1
    {
        int dot = t >> 3, sub = t & 7;           // 32 dots x 8 threads
        int p = dot >> 3, h = dot & 7;
        const float* q = (p & 2) ? mrow : row;
        const float* k = ((p & 1) ? mrow : row) + C;
        float a = 0.f;
        int base = h * D + sub * (D / 8);
        #pragma unroll
        for (int i = 0; i < D / 8; ++i) a += q[base + i] * k[base + i];
        a += __shfl_xor(a, 4, 8); a += __shfl_xor(a, 2, 8); a += __shfl_xor(a, 1, 8);
        if (sub == 0) sred[dot] = a;
    }
    {
        int g = t >> 4, sub = t & 15;            // 16 gate dots x 16 threads
        int s = g >> 3, h = g & 7;
        const float* x = A1 + (size_t)(s ? (MROW + n) : r) * lda;
        float a = 0.f;
        for (int i = sub; i < C; i += 16) a += x[i] * wg[i * 8 + h];
        a += __shfl_xor(a, 8, 16); a += __shfl_xor(a, 4, 16);
        a += __shfl_xor(a, 2, 16); a += __shfl_xor(a, 1, 16);
        if (sub == 0) sred[32 + g] = 1.0f / (1.0f + expf(-(a + bg[h])));
    }
    __syncthreads();
    if (t < 8) {
        int h = t;
        float scale = (float)(1.0 / sqrt((double)D));
        float c0 = 0.f, c1 = 0.f;
        #pragma unroll
        for (int s = 0; s < 2; ++s) {
            float a0 = sred[(2 * s) * 8 + h] * scale;
            float a1 = sred[(2 * s + 1) * 8 + h] * scale;
            float mx = fmaxf(a0, a1);
            float e0 = expf(a0 - mx), e1 = expf(a1 - mx);
            float inv = 1.0f / (e0 + e1);
            float gt = sred[32 + s * 8 + h];
            c0 += e0 * inv * gt;
            c1 += e1 * inv * gt;
        }
        sred[48 + h] = 0.5f * c0;
        sred[56 + h] = 0.5f * c1;
    }
    __syncthreads();
    const float* v0 = row + 2 * C;
    const float* v1 = mrow + 2 * C;
    for (int c = t; c < C; c += 256) {
        int h = c / D;
        om[(size_t)r * C + c] = sred[48 + h] * v0[c] + sred[56 + h] * v1[c];
    }
}

struct MidP {
    GP gp; int ngemm;
    const float *qkv1, *qkv0, *A1_1, *A1_0, *wg1, *bg1, *wg0, *bg0;
    float *om1, *om0;
};
__global__ __launch_bounds__(256) void mid(MidP P)
{
    __shared__ char smem[64 * 72 * 2 + 128 * 72 * 2];
    int bid = blockIdx.x;
    if (bid < P.ngemm) {
        int i = 0;
        while (i + 1 < P.gp.nd && bid >= P.gp.blk0[i + 1]) ++i;
        gemm_block(P.gp.d[i], bid - P.gp.blk0[i], smem);
    } else if (bid < P.ngemm + 1088) {
        int a = bid - P.ngemm;
        float* sred = (float*)smem;
        if (a < 544) attn_row<512>(a, P.qkv1, P.A1_1, 1024, P.wg1, P.bg1, P.om1, sred);
        else         attn_row<256>(a - 544, P.qkv0, P.A1_0, 512, P.wg0, P.bg0, P.om0, sred);
    } else {
        int u = bid - P.ngemm - 1088;
        int lvl1 = u < 32;
        int row = MROW + (u & 31);
        int C = lvl1 ? 512 : 256;
        float* om = (lvl1 ? P.om1 : P.om0) + (size_t)row * C;
        for (int c = threadIdx.x; c < C; c += 256) om[c] = 0.f;
    }
}

// --------------------------------------------- fallback (round-2 kernel) --
template<int C, int H, int W>
__global__ __launch_bounds__(C) void fb_level(
    const float* __restrict__ fm, const float* __restrict__ kp,
    const float* __restrict__ ms, const float* __restrict__ w1,
    const float* __restrict__ b1, const float* __restrict__ gvec,
    const float* __restrict__ beta, const float* __restrict__ w2,
    const float* __restrict__ b2, const float* __restrict__ wqkv,
    const float* __restrict__ bqkv, const float* __restrict__ wg,
    const float* __restrict__ bg, const float* __restrict__ wo,
    const float* __restrict__ bo, float* __restrict__ out)
{
    constexpr int D = C / 8;
    constexpr int NW = C / 64;
    __shared__ float x0[C], x1[C], hbuf[C];
    __shared__ float q0[C], k0[C], v0[C], q1[C], k1[C], v1[C];
    __shared__ float om[C];
    __shared__ float gw[25];
    __shared__ float gwsum_inv;
    __shared__ float redA[NW], redB[NW];
    __shared__ float stats[2];
    __shared__ float gates[2][8];
    __shared__ float att[2][2][8];
    const int j = threadIdx.x;
    const int blk = blockIdx.x;
    const int b = blk / NKPT, n = blk % NKPT;
    if (j < 25) { int dy = j / 5 - 2, dx = j % 5 - 2; gw[j] = expf(-(float)(dy*dy+dx*dx) / 8.0f); }
    __syncthreads();
    if (j == 0) { float s = 0.f; for (int t2 = 0; t2 < 25; ++t2) s += gw[t2]; gwsum_inv = 1.0f / s; }
    float kx = kp[(b * NKPT + n) * 2 + 0];
    float ky = kp[(b * NKPT + n) * 2 + 1];
    int cx = (int)rintf(kx * ((float)W / 192.0f));
    int cy = (int)rintf(ky * ((float)H / 256.0f));
    int ix[5], iy[5];
    #pragma unroll
    for (int t2 = 0; t2 < 5; ++t2) {
        ix[t2] = min(max(cx + t2 - 2, 0), W - 1);
        iy[t2] = min(max(cy + t2 - 2, 0), H - 1);
    }
    __syncthreads();
    {
        const float* fmb = fm + ((size_t)b * C + j) * (H * W);
        float acc = 0.f;
        #pragma unroll
        for (int yy = 0; yy < 5; ++yy) {
            const float* row = fmb + iy[yy] * W;
            #pragma unroll
            for (int xx = 0; xx < 5; ++xx) acc += gw[yy * 5 + xx] * row[ix[xx]];
        }
        x0[j] = acc * gwsum_inv;
        x1[j] = ms[n * C + j];
    }
    __syncthreads();
    float hacc = b1[j];
    for (int i = 0; i < C; ++i) hacc += x0[i] * w1[i * C + j];
    for (int i = 0; i < C; ++i) hacc += x1[i] * w1[(C + i) * C + j];
    {
        float s1 = hacc, s2 = hacc * hacc;
        #pragma unroll
        for (int o = 32; o > 0; o >>= 1) { s1 += __shfl_down(s1, o); s2 += __shfl_down(s2, o); }
        int lane = j & 63, wid = j >> 6;
        if (lane == 0) { redA[wid] = s1; redB[wid] = s2; }
        __syncthreads();
        if (j == 0) {
            float t1 = 0.f, t2 = 0.f;
            for (int w = 0; w < NW; ++w) { t1 += redA[w]; t2 += redB[w]; }
            float m = t1 / (float)C, v = t2 / (float)C - m * m;
            stats[0] = m; stats[1] = 1.0f / sqrtf(v + 1e-5f);
        }
        __syncthreads();
    }
    hbuf[j] = fmaxf((hacc - stats[0]) * stats[1] * gvec[j] + beta[j], 0.f);
    __syncthreads();
    float pj = b2[j];
    for (int i = 0; i < C; ++i) pj += hbuf[i] * w2[i * C + j];
    {
        float aq0 = bqkv[j], ak0 = bqkv[C + j], av0 = bqkv[2 * C + j];
        float aq1 = aq0, ak1 = ak0, av1 = av0;
        for (int i = 0; i < C; ++i) {
            float xi0 = x0[i], xi1 = x1[i];
            const float* wr = wqkv + (size_t)i * (3 * C);
            float wq = wr[j], wk = wr[C + j], wv = wr[2 * C + j];
            aq0 += xi0 * wq; aq1 += xi1 * wq;
            ak0 += xi0 * wk; ak1 += xi1 * wk;
            av0 += xi0 * wv; av1 += xi1 * wv;
        }
        q0[j] = aq0; k0[j] = ak0; v0[j] = av0;
        q1[j] = aq1; k1[j] = ak1; v1[j] = av1;
    }
    __syncthreads();
    if (j < 16) {
        int s = j >> 3, hh = j & 7;
        const float* xs = s ? x1 : x0;
        float a = bg[hh];
        for (int i = 0; i < C; ++i) a += xs[i] * wg[i * 8 + hh];
        gates[s][hh] = 1.0f / (1.0f + expf(-a));
    }
    if (j < 32) {
        int hh = j >> 2, st = j & 3;
        const float* qs = (st & 2) ? q1 : q0;
        const float* kt = (st & 1) ? k1 : k0;
        float a = 0.f;
        for (int i = hh * D; i < (hh + 1) * D; ++i) a += qs[i] * kt[i];
        att[(st >> 1)][st & 1][hh] = a;
    }
    __syncthreads();
    if (j < 16) {
        int s = j >> 3, hh = j & 7;
        const float inv = 1.0f / sqrtf((float)D);
        float a0 = att[s][0][hh] * inv, a1 = att[s][1][hh] * inv;
        float mx = fmaxf(a0, a1);
        float e0 = expf(a0 - mx), e1 = expf(a1 - mx);
        float den = e0 + e1;
        att[s][0][hh] = e0 / den; att[s][1][hh] = e1 / den;
    }
    __syncthreads();
    {
        int hh = j / D;
        float o0 = (att[0][0][hh] * v0[j] + att[0][1][hh] * v1[j]) * gates[0][hh];
        float o1 = (att[1][0][hh] * v0[j] + att[1][1][hh] * v1[j]) * gates[1][hh];
        om[j] = 0.5f * (o0 + o1);
    }
    __syncthreads();
    float oacc = bo[j];
    for (int i = 0; i < C; ++i) oacc += om[i] * wo[i * C + j];
    out[((size_t)b * NKPT + n) * C + j] = oacc + pj;
}

// ------------------------------------------------------------- launch -----
extern "C" void kernel_launch(void* const* d_in, const int* in_sizes, int n_in,
                              void* d_out, int out_size, void* d_ws, size_t ws_size,
                              hipStream_t stream) {
    (void)in_sizes; (void)n_in; (void)out_size;
    const float* fm0  = (const float*)d_in[0];
    const float* fm1  = (const float*)d_in[1];
    const float* kp   = (const float*)d_in[2];
    const float* ms0     = (const float*)d_in[3];
    const float* p0_w1   = (const float*)d_in[4];
    const float* p0_b1   = (const float*)d_in[5];
    const float* p0_g    = (const float*)d_in[6];
    const float* p0_beta = (const float*)d_in[7];
    const float* p0_w2   = (const float*)d_in[8];
    const float* p0_b2   = (const float*)d_in[9];
    const float* a0_wqkv = (const float*)d_in[10];
    const float* a0_bqkv = (const float*)d_in[11];
    const float* a0_wg   = (const float*)d_in[12];
    const float* a0_bg   = (const float*)d_in[13];
    const float* a0_wo   = (const float*)d_in[14];
    const float* a0_bo   = (const float*)d_in[15];
    const float* ms1     = (const float*)d_in[16];
    const float* p1_w1   = (const float*)d_in[17];
    const float* p1_b1   = (const float*)d_in[18];
    const float* p1_g    = (const float*)d_in[19];
    const float* p1_beta = (const float*)d_in[20];
    const float* p1_w2   = (const float*)d_in[21];
    const float* p1_b2   = (const float*)d_in[22];
    const float* a1_wqkv = (const float*)d_in[23];
    const float* a1_bqkv = (const float*)d_in[24];
    const float* a1_wg   = (const float*)d_in[25];
    const float* a1_bg   = (const float*)d_in[26];
    const float* a1_wo   = (const float*)d_in[27];
    const float* a1_bo   = (const float*)d_in[28];

    float* out0 = (float*)d_out;                               // (544,256)
    float* out1 = (float*)d_out + (size_t)MROW * 256;          // (544,512)

    const size_t WS_NEED = 18743296;
    if (ws_size < WS_NEED || d_ws == nullptr) {
        // fallback: proven round-2 kernels
        fb_level<256, 96, 72><<<MROW, 256, 0, stream>>>(
            fm0, kp, ms0, p0_w1, p0_b1, p0_g, p0_beta, p0_w2, p0_b2,
            a0_wqkv, a0_bqkv, a0_wg, a0_bg, a0_wo, a0_bo, out0);
        fb_level<512, 48, 36><<<MROW, 512, 0, stream>>>(
            fm1, kp, ms1, p1_w1, p1_b1, p1_g, p1_beta, p1_w2, p1_b2,
            a1_wqkv, a1_bqkv, a1_wg, a1_bg, a1_wo, a1_bo, out1);
        return;
    }

    char* cur = (char*)d_ws;
    auto alloc = [&](size_t bytes) { char* p = cur; cur += (bytes + 255) & ~(size_t)255; return p; };
    float* A1_1  = (float*)alloc((size_t)MPAD * 1024 * 4);
    float* A1_0  = (float*)alloc((size_t)MPAD * 512 * 4);
    float* h_1   = (float*)alloc((size_t)MPAD * 512 * 4);
    float* h_0   = (float*)alloc((size_t)MPAD * 256 * 4);
    float* pj_1  = (float*)alloc((size_t)MPAD * 512 * 4);
    float* pj_0  = (float*)alloc((size_t)MPAD * 256 * 4);
    float* qkv_1 = (float*)alloc((size_t)MPAD * 1536 * 4);
    float* qkv_0 = (float*)alloc((size_t)MPAD * 768 * 4);
    float* om_1  = (float*)alloc((size_t)MPAD * 512 * 4);
    float* om_0  = (float*)alloc((size_t)MPAD * 256 * 4);
    u16* w1T_1   = (u16*)alloc((size_t)512 * 1024 * 2);
    u16* wqkvT_1 = (u16*)alloc((size_t)1536 * 512 * 2);
    u16* w2T_1   = (u16*)alloc((size_t)512 * 512 * 2);
    u16* woT_1   = (u16*)alloc((size_t)512 * 512 * 2);
    u16* w1T_0   = (u16*)alloc((size_t)256 * 512 * 2);
    u16* wqkvT_0 = (u16*)alloc((size_t)768 * 256 * 2);
    u16* w2T_0   = (u16*)alloc((size_t)256 * 256 * 2);
    u16* woT_0   = (u16*)alloc((size_t)256 * 256 * 2);

    // ---- L1: pool + meta/zero + weight transpose/convert ----
    PrepP pp;
    pp.fm0 = fm0; pp.fm1 = fm1; pp.kp = kp; pp.ms0 = ms0; pp.ms1 = ms1;
    pp.A1_0 = A1_0; pp.A1_1 = A1_1;
    int tcum = 0;
    auto setTD = [&](int i, const float* src, u16* dst, int K, int N) {
        pp.td[i].src = src; pp.td[i].dst = dst; pp.td[i].K = K; pp.td[i].N = N;
        pp.td[i].blk0 = tcum; tcum += (K / 64) * (N / 64);
    };
    setTD(0, p1_w1,   w1T_1,   1024, 512);
    setTD(1, a1_wqkv, wqkvT_1, 512, 1536);
    setTD(2, p1_w2,   w2T_1,   512,  512);
    setTD(3, a1_wo,   woT_1,   512,  512);
    setTD(4, p0_w1,   w1T_0,   512,  256);
    setTD(5, a0_wqkv, wqkvT_0, 256,  768);
    setTD(6, p0_w2,   w2T_0,   256,  256);
    setTD(7, a0_wo,   woT_0,   256,  256);
    prep<<<1152 + tcum, 256, 0, stream>>>(pp);

    // ---- L2: GEMM w1 + wqkv (both levels) ----
    GP g2; g2.nd = 4;
    g2.d[0] = { A1_1, w1T_1,   p1_b1,   nullptr, h_1,   1024, 512,  1024, 512,  MPAD, 4 };
    g2.d[1] = { A1_1, wqkvT_1, a1_bqkv, nullptr, qkv_1, 1024, 1536, 512,  1536, MPAD, 12 };
    g2.d[2] = { A1_0, w1T_0,   p0_b1,   nullptr, h_0,   512,  256,  512,  256,  MPAD, 2 };
    g2.d[3] = { A1_0, wqkvT_0, a0_bqkv, nullptr, qkv_0, 512,  768,  256,  768,  MPAD, 6 };
    g2.blk0[0] = 0;
    for (int i = 0; i < 4; ++i) g2.blk0[i + 1] = g2.blk0[i] + 9 * g2.d[i].ntiles;
    gemm_multi<<<g2.blk0[4], 256, 0, stream>>>(g2);

    // ---- L3: LayerNorm + relu ----
    LnP lp{ h_1, h_0, p1_g, p1_beta, p0_g, p0_beta };
    lnrelu<<<1088, 256, 0, stream>>>(lp);

    // ---- L4: w2-GEMM (projected) || attention+gates ----
    MidP mp;
    mp.gp.nd = 2;
    mp.gp.d[0] = { h_1, w2T_1, p1_b2, nullptr, pj_1, 512, 512, 512, 512, MPAD, 4 };
    mp.gp.d[1] = { h_0, w2T_0, p0_b2, nullptr, pj_0, 256, 256, 256, 256, MPAD, 2 };
    mp.gp.blk0[0] = 0;
    for (int i = 0; i < 2; ++i) mp.gp.blk0[i + 1] = mp.gp.blk0[i] + 9 * mp.gp.d[i].ntiles;
    mp.ngemm = mp.gp.blk0[2];
    mp.qkv1 = qkv_1; mp.qkv0 = qkv_0; mp.A1_1 = A1_1; mp.A1_0 = A1_0;
    mp.wg1 = a1_wg; mp.bg1 = a1_bg; mp.wg0 = a0_wg; mp.bg0 = a0_bg;
    mp.om1 = om_1; mp.om0 = om_0;
    mid<<<mp.ngemm + 1088 + 64, 256, 0, stream>>>(mp);

    // ---- L5: wo-GEMM + bias + projected -> out ----
    GP g5; g5.nd = 2;
    g5.d[0] = { om_1, woT_1, a1_bo, pj_1, out1, 512, 512, 512, 512, MROW, 4 };
    g5.d[1] = { om_0, woT_0, a0_bo, pj_0, out0, 256, 256, 256, 256, MROW, 2 };
    g5.blk0[0] = 0;
    for (int i = 0; i < 2; ++i) g5.blk0[i + 1] = g5.blk0[i] + 9 * g5.d[i].ntiles;
    gemm_multi<<<g5.blk0[2], 256, 0, stream>>>(g5);
}

// Round 6
// 106.737 us; speedup vs baseline: 3.6878x; 1.2363x over previous
//
#include <hip/hip_runtime.h>
#include <math.h>

#define NKPT 17
#define BATCH 32
#define MROW 544          // BATCH*NKPT
#define MPAD 576          // 9*64

typedef unsigned short u16;
typedef _Float16 half8 __attribute__((ext_vector_type(8)));
typedef float f32x4 __attribute__((ext_vector_type(4)));

__device__ __forceinline__ u16 f2h(float f) {
    _Float16 h = (_Float16)f;
    u16 u; __builtin_memcpy(&u, &h, 2); return u;
}

// ---------------------------------------------------------------- GEMM ----
// BM=64, BN=64, BK=64, 256 threads (4 waves as 2x2 of 32x32).
// A: fp16 [Mpad][lda]. BT: fp16 [N][K]. dst: f32, atomicAdd (pre-zeroed).
// sk=2 splits K; bias added by the s==0 block only.
struct GD {
    const u16* A; const u16* BT; const float* bias; float* dst;
    int lda, ldd, K, N, mstore, ntiles, sk;
};
struct GP { GD d[4]; int blk0[5]; int nd; };

__global__ __launch_bounds__(256) void gemm_fp16(GP P)
{
    __shared__ u16 sA[64][72];
    __shared__ u16 sB[64][72];
    int bid = blockIdx.x, gi = 0;
    while (gi + 1 < P.nd && bid >= P.blk0[gi + 1]) ++gi;
    const GD g = P.d[gi];
    int local = bid - P.blk0[gi];
    const int nspan = g.ntiles * g.sk;
    const int mt = local / nspan;
    int rem = local - mt * nspan;
    const int nt = rem / g.sk;
    const int s  = rem - nt * g.sk;
    const int m0 = mt * 64, n0 = nt * 64;
    const int Kseg = g.K / g.sk;
    const int kbase = s * Kseg;

    const int t = threadIdx.x;
    const int l = t & 63, w = t >> 6, wr = w >> 1, wc = w & 1;
    const int row = t >> 2, kc = (t & 3) << 4;

    f32x4 acc[2][2];
    #pragma unroll
    for (int i = 0; i < 2; ++i)
        #pragma unroll
        for (int j = 0; j < 2; ++j) { f32x4 z = {0.f,0.f,0.f,0.f}; acc[i][j] = z; }

    const u16* ap = g.A  + (size_t)(m0 + row) * g.lda + kbase + kc;
    const u16* bp = g.BT + (size_t)(n0 + row) * g.K   + kbase + kc;
    uint4 ra0 = *(const uint4*)ap,       ra1 = *(const uint4*)(ap + 8);
    uint4 rb0 = *(const uint4*)bp,       rb1 = *(const uint4*)(bp + 8);

    for (int k0 = 0; k0 < Kseg; k0 += 64) {
        __syncthreads();
        *(uint4*)&sA[row][kc] = ra0; *(uint4*)&sA[row][kc + 8] = ra1;
        *(uint4*)&sB[row][kc] = rb0; *(uint4*)&sB[row][kc + 8] = rb1;
        __syncthreads();
        if (k0 + 64 < Kseg) {   // prefetch next tile under the MFMAs
            ra0 = *(const uint4*)(ap + k0 + 64); ra1 = *(const uint4*)(ap + k0 + 72);
            rb0 = *(const uint4*)(bp + k0 + 64); rb1 = *(const uint4*)(bp + k0 + 72);
        }
        #pragma unroll
        for (int ks = 0; ks < 64; ks += 32) {
            const int koff = ks + (l >> 4) * 8;
            half8 af0 = *(const half8*)&sA[wr * 32 +      (l & 15)][koff];
            half8 af1 = *(const half8*)&sA[wr * 32 + 16 + (l & 15)][koff];
            half8 bf0 = *(const half8*)&sB[wc * 32 +      (l & 15)][koff];
            half8 bf1 = *(const half8*)&sB[wc * 32 + 16 + (l & 15)][koff];
            acc[0][0] = __builtin_amdgcn_mfma_f32_16x16x32_f16(af0, bf0, acc[0][0], 0, 0, 0);
            acc[0][1] = __builtin_amdgcn_mfma_f32_16x16x32_f16(af0, bf1, acc[0][1], 0, 0, 0);
            acc[1][0] = __builtin_amdgcn_mfma_f32_16x16x32_f16(af1, bf0, acc[1][0], 0, 0, 0);
            acc[1][1] = __builtin_amdgcn_mfma_f32_16x16x32_f16(af1, bf1, acc[1][1], 0, 0, 0);
        }
    }

    // D layout: col = l&15 (within frag), row = (l>>4)*4 + reg  (verified)
    #pragma unroll
    for (int i = 0; i < 2; ++i) {
        #pragma unroll
        for (int j = 0; j < 2; ++j) {
            int col = n0 + wc * 32 + j * 16 + (l & 15);
            float bv = (s == 0) ? g.bias[col] : 0.f;
            #pragma unroll
            for (int rr = 0; rr < 4; ++rr) {
                int m = m0 + wr * 32 + i * 16 + (l >> 4) * 4 + rr;
                if (m < g.mstore)
                    atomicAdd(&g.dst[(size_t)m * g.ldd + col], acc[i][j][rr] + bv);
            }
        }
    }
}

// ---------------------------------------------------------------- prep ----
struct TD { const float* src; u16* dst; int K, N, blk0; };
struct PrepP {
    const float *fm0, *fm1, *kp, *ms0, *ms1;
    float *A1_0, *A1_1;      // f32 [MPAD][2C] (rows 0..560 used; gates only)
    u16 *A1h_0, *A1h_1;      // fp16 [MPAD][2C] (GEMM A)
    char* zbase;             // contiguous zero region (h,qkv,h16,om16)
    float* out;              // d_out base (zeroed here)
    TD td[8];
};

__device__ void zero_chunk(char* base, size_t bytes, int u)
{
    size_t off = (size_t)u * 65536 + (size_t)threadIdx.x * 16;
    #pragma unroll
    for (int r = 0; r < 16; ++r) {
        size_t o = off + (size_t)r * 4096;
        if (o + 16 <= bytes) *(float4*)(base + o) = make_float4(0.f, 0.f, 0.f, 0.f);
    }
}

template<int C, int H, int W>
__device__ void pool_row(int b, int n, const float* fm, const float* kp,
                         const float* ms, float* A1, u16* A1h, float* sg)
{
    const int t = threadIdx.x;
    if (t < 25) {
        int dy = t / 5 - 2, dx = t % 5 - 2;
        sg[t] = expf(-(float)(dy * dy + dx * dx) / 8.0f);
    }
    __syncthreads();
    if (t == 0) {
        float s = 0.f;
        #pragma unroll
        for (int u2 = 0; u2 < 25; ++u2) s += sg[u2];
        sg[25] = 1.0f / s;
    }
    __syncthreads();
    float kx = kp[(b * NKPT + n) * 2 + 0];
    float ky = kp[(b * NKPT + n) * 2 + 1];
    int cx = (int)rintf(kx * ((float)W / 192.0f));   // RNE == jnp.round
    int cy = (int)rintf(ky * ((float)H / 256.0f));
    int ix[5], iy[5];
    #pragma unroll
    for (int q = 0; q < 5; ++q) {
        ix[q] = min(max(cx + q - 2, 0), W - 1);
        iy[q] = min(max(cy + q - 2, 0), H - 1);
    }
    const float inv = sg[25];
    float* rowf = A1  + (size_t)(b * NKPT + n) * (2 * C);
    u16*   rowh = A1h + (size_t)(b * NKPT + n) * (2 * C);
    for (int c = t; c < C; c += 256) {
        const float* fmb = fm + ((size_t)b * C + c) * (H * W);
        float acc = 0.f;
        #pragma unroll
        for (int yy = 0; yy < 5; ++yy) {
            const float* rr = fmb + iy[yy] * W;
            #pragma unroll
            for (int xx = 0; xx < 5; ++xx) acc += sg[yy * 5 + xx] * rr[ix[xx]];
        }
        float val = acc * inv;
        float msv = ms[n * C + c];
        rowf[c] = val;      rowf[C + c] = msv;
        rowh[c] = f2h(val); rowh[C + c] = f2h(msv);
    }
}

template<int C>
__device__ void meta_row(int n, const float* ms, float* A1, u16* A1h)
{
    float* rowf = A1  + (size_t)(MROW + n) * (2 * C);
    u16*   rowh = A1h + (size_t)(MROW + n) * (2 * C);
    for (int c = threadIdx.x; c < C; c += 256) {
        float v = ms[n * C + c];
        rowf[c] = v;       rowf[C + c] = 0.f;
        rowh[c] = f2h(v);  rowh[C + c] = 0;
    }
}

__device__ void wtrans_tile(const TD& d, int u, float* sT)  // sT: [64][65] f32
{
    const int ntx = d.N >> 6;
    const int tk = u / ntx, tn = u % ntx;
    const int k0 = tk << 6, n0 = tn << 6;
    const int t = threadIdx.x;
    {
        int r = t >> 2, cq = (t & 3) << 4;
        const float* sp = d.src + (size_t)(k0 + r) * d.N + n0 + cq;
        #pragma unroll
        for (int i = 0; i < 4; ++i) {
            float4 v = *(const float4*)(sp + 4 * i);
            sT[r * 65 + cq + 4 * i + 0] = v.x;
            sT[r * 65 + cq + 4 * i + 1] = v.y;
            sT[r * 65 + cq + 4 * i + 2] = v.z;
            sT[r * 65 + cq + 4 * i + 3] = v.w;
        }
    }
    __syncthreads();
    {
        int nn = t >> 2, kq = (t & 3) << 4;
        u16 hv[16] __attribute__((aligned(16)));
        #pragma unroll
        for (int i = 0; i < 16; ++i) hv[i] = f2h(sT[(kq + i) * 65 + nn]);
        u16* dp = d.dst + (size_t)(n0 + nn) * d.K + k0 + kq;
        *reinterpret_cast<uint4*>(dp) = *reinterpret_cast<uint4*>(&hv[0]);
        *reinterpret_cast<uint4*>(dp + 8) = *reinterpret_cast<uint4*>(&hv[8]);
    }
}

__global__ __launch_bounds__(256) void k1_prep(PrepP P)
{
    __shared__ float ps[64 * 65];
    int bid = blockIdx.x;
    if (bid < 1088) {
        if (bid < 544) pool_row<512, 48, 36>(bid / NKPT, bid % NKPT, P.fm1, P.kp, P.ms1, P.A1_1, P.A1h_1, ps);
        else { int r = bid - 544; pool_row<256, 96, 72>(r / NKPT, r % NKPT, P.fm0, P.kp, P.ms0, P.A1_0, P.A1h_0, ps); }
    } else if (bid < 1122) {
        int u = bid - 1088;
        if (u < NKPT) meta_row<512>(u, P.ms1, P.A1_1, P.A1h_1);
        else          meta_row<256>(u - NKPT, P.ms0, P.A1_0, P.A1h_0);
    } else if (bid < 1682) {
        int u = bid - 1122, i = 0;
        while (i + 1 < 8 && u >= P.td[i + 1].blk0) ++i;
        wtrans_tile(P.td[i], u - P.td[i].blk0, ps);
    } else if (bid < 1817) {
        zero_chunk(P.zbase, 8847360, bid - 1682);
    } else if (bid < 1843) {
        zero_chunk((char*)P.out, (size_t)417792 * 4, bid - 1817);
    } else if (bid == 1843) {
        zero_chunk((char*)(P.A1h_1 + (size_t)561 * 1024), 30720, 0);
    } else {
        zero_chunk((char*)(P.A1h_0 + (size_t)561 * 512), 15360, 0);
    }
}

// ----------------------------------------------- rowops: LN+relu / attn ---
template<int C>
__device__ void attn_row(int r, const float* qkv, const float* A1, int lda,
                         const float* wg, const float* bg, u16* om, float* sred)
{
    constexpr int D = C / 8;
    constexpr int TC = 3 * C;
    const int t = threadIdx.x;
    const int n = r % NKPT;
    const float* row  = qkv + (size_t)r * TC;
    const float* mrow = qkv + (size_t)(MROW + n) * TC;
    {
        int dot = t >> 3, sub = t & 7;           // 32 dots x 8 threads
        int p = dot >> 3, h = dot & 7;
        const float* q = (p & 2) ? mrow : row;
        const float* k = ((p & 1) ? mrow : row) + C;
        float a = 0.f;
        int base = h * D + sub * (D / 8);
        #pragma unroll
        for (int i = 0; i < D / 8; ++i) a += q[base + i] * k[base + i];
        a += __shfl_xor(a, 4, 8); a += __shfl_xor(a, 2, 8); a += __shfl_xor(a, 1, 8);
        if (sub == 0) sred[dot] = a;
    }
    {
        int g = t >> 4, sub = t & 15;            // 16 gate dots x 16 threads
        int s = g >> 3, h = g & 7;
        const float* x = A1 + (size_t)(s ? (MROW + n) : r) * lda;
        float a = 0.f;
        for (int i = sub; i < C; i += 16) a += x[i] * wg[i * 8 + h];
        a += __shfl_xor(a, 8, 16); a += __shfl_xor(a, 4, 16);
        a += __shfl_xor(a, 2, 16); a += __shfl_xor(a, 1, 16);
        if (sub == 0) sred[32 + g] = 1.0f / (1.0f + expf(-(a + bg[h])));
    }
    __syncthreads();
    if (t < 8) {
        int h = t;
        float scale = (float)(1.0 / sqrt((double)D));
        float c0 = 0.f, c1 = 0.f;
        #pragma unroll
        for (int s = 0; s < 2; ++s) {
            float a0 = sred[(2 * s) * 8 + h] * scale;
            float a1 = sred[(2 * s + 1) * 8 + h] * scale;
            float mx = fmaxf(a0, a1);
            float e0 = expf(a0 - mx), e1 = expf(a1 - mx);
            float inv = 1.0f / (e0 + e1);
            float gt = sred[32 + s * 8 + h];
            c0 += e0 * inv * gt;
            c1 += e1 * inv * gt;
        }
        sred[48 + h] = 0.5f * c0;
        sred[56 + h] = 0.5f * c1;
    }
    __syncthreads();
    const float* v0 = row + 2 * C;
    const float* v1 = mrow + 2 * C;
    for (int c = t; c < C; c += 256) {
        int h = c / D;
        om[(size_t)r * C + c] = f2h(sred[48 + h] * v0[c] + sred[56 + h] * v1[c]);
    }
}

struct RP {
    const float *h1, *h0; u16 *h16_1, *h16_0;
    const float *g1, *be1, *g0, *be0;
    const float *qkv1, *qkv0, *A1_1, *A1_0;
    const float *wg1, *bg1, *wg0, *bg0;
    u16 *om1, *om0;
};
__global__ __launch_bounds__(256) void k3_rowops(RP P)
{
    __shared__ float sh[64];
    int bid = blockIdx.x;
    if (bid < 1088) {
        int lvl1 = bid < 544;
        int r = lvl1 ? bid : bid - 544;
        int C = lvl1 ? 512 : 256;
        const float* h = (lvl1 ? P.h1 : P.h0) + (size_t)r * C;
        u16* h16 = (lvl1 ? P.h16_1 : P.h16_0) + (size_t)r * C;
        const float* gg = lvl1 ? P.g1 : P.g0;
        const float* bb = lvl1 ? P.be1 : P.be0;
        int t = threadIdx.x;
        int nc = C >> 8;
        float v[2] = {0.f, 0.f};
        float s1 = 0.f, s2 = 0.f;
        for (int i = 0; i < nc; ++i) { float x = h[t + (i << 8)]; v[i] = x; s1 += x; s2 += x * x; }
        #pragma unroll
        for (int o = 32; o > 0; o >>= 1) { s1 += __shfl_down(s1, o); s2 += __shfl_down(s2, o); }
        int lane = t & 63, wv = t >> 6;
        if (lane == 0) { sh[wv * 2] = s1; sh[wv * 2 + 1] = s2; }
        __syncthreads();
        if (t == 0) {
            float a = 0.f, b = 0.f;
            #pragma unroll
            for (int q = 0; q < 4; ++q) { a += sh[q * 2]; b += sh[q * 2 + 1]; }
            float m = a / (float)C;
            float var = b / (float)C - m * m;
            sh[8] = m; sh[9] = 1.0f / sqrtf(var + 1e-5f);
        }
        __syncthreads();
        float m = sh[8], rs = sh[9];
        for (int i = 0; i < nc; ++i) {
            int c = t + (i << 8);
            float x = (v[i] - m) * rs * gg[c] + bb[c];
            h16[c] = f2h(fmaxf(x, 0.f));
        }
    } else {
        int a = bid - 1088;
        if (a < 544) attn_row<512>(a, P.qkv1, P.A1_1, 1024, P.wg1, P.bg1, P.om1, sh);
        else         attn_row<256>(a - 544, P.qkv0, P.A1_0, 512, P.wg0, P.bg0, P.om0, sh);
    }
}

// --------------------------------------------- fallback (round-2 kernel) --
template<int C, int H, int W>
__global__ __launch_bounds__(C) void fb_level(
    const float* __restrict__ fm, const float* __restrict__ kp,
    const float* __restrict__ ms, const float* __restrict__ w1,
    const float* __restrict__ b1, const float* __restrict__ gvec,
    const float* __restrict__ beta, const float* __restrict__ w2,
    const float* __restrict__ b2, const float* __restrict__ wqkv,
    const float* __restrict__ bqkv, const float* __restrict__ wg,
    const float* __restrict__ bg, const float* __restrict__ wo,
    const float* __restrict__ bo, float* __restrict__ out)
{
    constexpr int D = C / 8;
    constexpr int NW = C / 64;
    __shared__ float x0[C], x1[C], hbuf[C];
    __shared__ float q0[C], k0[C], v0[C], q1[C], k1[C], v1[C];
    __shared__ float om[C];
    __shared__ float gw[25];
    __shared__ float gwsum_inv;
    __shared__ float redA[NW], redB[NW];
    __shared__ float stats[2];
    __shared__ float gates[2][8];
    __shared__ float att[2][2][8];
    const int j = threadIdx.x;
    const int blk = blockIdx.x;
    const int b = blk / NKPT, n = blk % NKPT;
    if (j < 25) { int dy = j / 5 - 2, dx = j % 5 - 2; gw[j] = expf(-(float)(dy*dy+dx*dx) / 8.0f); }
    __syncthreads();
    if (j == 0) { float s = 0.f; for (int t2 = 0; t2 < 25; ++t2) s += gw[t2]; gwsum_inv = 1.0f / s; }
    float kx = kp[(b * NKPT + n) * 2 + 0];
    float ky = kp[(b * NKPT + n) * 2 + 1];
    int cx = (int)rintf(kx * ((float)W / 192.0f));
    int cy = (int)rintf(ky * ((float)H / 256.0f));
    int ix[5], iy[5];
    #pragma unroll
    for (int t2 = 0; t2 < 5; ++t2) {
        ix[t2] = min(max(cx + t2 - 2, 0), W - 1);
        iy[t2] = min(max(cy + t2 - 2, 0), H - 1);
    }
    __syncthreads();
    {
        const float* fmb = fm + ((size_t)b * C + j) * (H * W);
        float acc = 0.f;
        #pragma unroll
        for (int yy = 0; yy < 5; ++yy) {
            const float* row = fmb + iy[yy] * W;
            #pragma unroll
            for (int xx = 0; xx < 5; ++xx) acc += gw[yy * 5 + xx] * row[ix[xx]];
        }
        x0[j] = acc * gwsum_inv;
        x1[j] = ms[n * C + j];
    }
    __syncthreads();
    float hacc = b1[j];
    for (int i = 0; i < C; ++i) hacc += x0[i] * w1[i * C + j];
    for (int i = 0; i < C; ++i) hacc += x1[i] * w1[(C + i) * C + j];
    {
        float s1 = hacc, s2 = hacc * hacc;
        #pragma unroll
        for (int o = 32; o > 0; o >>= 1) { s1 += __shfl_down(s1, o); s2 += __shfl_down(s2, o); }
        int lane = j & 63, wid = j >> 6;
        if (lane == 0) { redA[wid] = s1; redB[wid] = s2; }
        __syncthreads();
        if (j == 0) {
            float t1 = 0.f, t2 = 0.f;
            for (int w = 0; w < NW; ++w) { t1 += redA[w]; t2 += redB[w]; }
            float m = t1 / (float)C, v = t2 / (float)C - m * m;
            stats[0] = m; stats[1] = 1.0f / sqrtf(v + 1e-5f);
        }
        __syncthreads();
    }
    hbuf[j] = fmaxf((hacc - stats[0]) * stats[1] * gvec[j] + beta[j], 0.f);
    __syncthreads();
    float pj = b2[j];
    for (int i = 0; i < C; ++i) pj += hbuf[i] * w2[i * C + j];
    {
        float aq0 = bqkv[j], ak0 = bqkv[C + j], av0 = bqkv[2 * C + j];
        float aq1 = aq0, ak1 = ak0, av1 = av0;
        for (int i = 0; i < C; ++i) {
            float xi0 = x0[i], xi1 = x1[i];
            const float* wr = wqkv + (size_t)i * (3 * C);
            float wq = wr[j], wk = wr[C + j], wv = wr[2 * C + j];
            aq0 += xi0 * wq; aq1 += xi1 * wq;
            ak0 += xi0 * wk; ak1 += xi1 * wk;
            av0 += xi0 * wv; av1 += xi1 * wv;
        }
        q0[j] = aq0; k0[j] = ak0; v0[j] = av0;
        q1[j] = aq1; k1[j] = ak1; v1[j] = av1;
    }
    __syncthreads();
    if (j < 16) {
        int s = j >> 3, hh = j & 7;
        const float* xs = s ? x1 : x0;
        float a = bg[hh];
        for (int i = 0; i < C; ++i) a += xs[i] * wg[i * 8 + hh];
        gates[s][hh] = 1.0f / (1.0f + expf(-a));
    }
    if (j < 32) {
        int hh = j >> 2, st = j & 3;
        const float* qs = (st & 2) ? q1 : q0;
        const float* kt = (st & 1) ? k1 : k0;
        float a = 0.f;
        for (int i = hh * D; i < (hh + 1) * D; ++i) a += qs[i] * kt[i];
        att[(st >> 1)][st & 1][hh] = a;
    }
    __syncthreads();
    if (j < 16) {
        int s = j >> 3, hh = j & 7;
        const float inv = 1.0f / sqrtf((float)D);
        float a0 = att[s][0][hh] * inv, a1 = att[s][1][hh] * inv;
        float mx = fmaxf(a0, a1);
        float e0 = expf(a0 - mx), e1 = expf(a1 - mx);
        float den = e0 + e1;
        att[s][0][hh] = e0 / den; att[s][1][hh] = e1 / den;
    }
    __syncthreads();
    {
        int hh = j / D;
        float o0 = (att[0][0][hh] * v0[j] + att[0][1][hh] * v1[j]) * gates[0][hh];
        float o1 = (att[1][0][hh] * v0[j] + att[1][1][hh] * v1[j]) * gates[1][hh];
        om[j] = 0.5f * (o0 + o1);
    }
    __syncthreads();
    float oacc = bo[j];
    for (int i = 0; i < C; ++i) oacc += om[i] * wo[i * C + j];
    out[((size_t)b * NKPT + n) * C + j] = oacc + pj;
}

// ------------------------------------------------------------- launch -----
extern "C" void kernel_launch(void* const* d_in, const int* in_sizes, int n_in,
                              void* d_out, int out_size, void* d_ws, size_t ws_size,
                              hipStream_t stream) {
    (void)in_sizes; (void)n_in; (void)out_size;
    const float* fm0  = (const float*)d_in[0];
    const float* fm1  = (const float*)d_in[1];
    const float* kp   = (const float*)d_in[2];
    const float* ms0     = (const float*)d_in[3];
    const float* p0_w1   = (const float*)d_in[4];
    const float* p0_b1   = (const float*)d_in[5];
    const float* p0_g    = (const float*)d_in[6];
    const float* p0_beta = (const float*)d_in[7];
    const float* p0_w2   = (const float*)d_in[8];
    const float* p0_b2   = (const float*)d_in[9];
    const float* a0_wqkv = (const float*)d_in[10];
    const float* a0_bqkv = (const float*)d_in[11];
    const float* a0_wg   = (const float*)d_in[12];
    const float* a0_bg   = (const float*)d_in[13];
    const float* a0_wo   = (const float*)d_in[14];
    const float* a0_bo   = (const float*)d_in[15];
    const float* ms1     = (const float*)d_in[16];
    const float* p1_w1   = (const float*)d_in[17];
    const float* p1_b1   = (const float*)d_in[18];
    const float* p1_g    = (const float*)d_in[19];
    const float* p1_beta = (const float*)d_in[20];
    const float* p1_w2   = (const float*)d_in[21];
    const float* p1_b2   = (const float*)d_in[22];
    const float* a1_wqkv = (const float*)d_in[23];
    const float* a1_bqkv = (const float*)d_in[24];
    const float* a1_wg   = (const float*)d_in[25];
    const float* a1_bg   = (const float*)d_in[26];
    const float* a1_wo   = (const float*)d_in[27];
    const float* a1_bo   = (const float*)d_in[28];

    float* out0 = (float*)d_out;                               // (544,256)
    float* out1 = (float*)d_out + (size_t)MROW * 256;          // (544,512)

    const size_t WS_NEED = 18743296;
    if (ws_size < WS_NEED || d_ws == nullptr) {
        fb_level<256, 96, 72><<<MROW, 256, 0, stream>>>(
            fm0, kp, ms0, p0_w1, p0_b1, p0_g, p0_beta, p0_w2, p0_b2,
            a0_wqkv, a0_bqkv, a0_wg, a0_bg, a0_wo, a0_bo, out0);
        fb_level<512, 48, 36><<<MROW, 512, 0, stream>>>(
            fm1, kp, ms1, p1_w1, p1_b1, p1_g, p1_beta, p1_w2, p1_b2,
            a1_wqkv, a1_bqkv, a1_wg, a1_bg, a1_wo, a1_bo, out1);
        return;
    }

    char* cur = (char*)d_ws;
    auto alloc = [&](size_t bytes) { char* p = cur; cur += (bytes + 255) & ~(size_t)255; return p; };
    float* A1_1  = (float*)alloc((size_t)MPAD * 1024 * 4);
    float* A1_0  = (float*)alloc((size_t)MPAD * 512 * 4);
    u16*   A1h_1 = (u16*)alloc((size_t)MPAD * 1024 * 2);
    u16*   A1h_0 = (u16*)alloc((size_t)MPAD * 512 * 2);
    // ---- contiguous zero region (8,847,360 B) ----
    char*  zbase = cur;
    float* h_1   = (float*)alloc((size_t)MPAD * 512 * 4);
    float* h_0   = (float*)alloc((size_t)MPAD * 256 * 4);
    float* qkv_1 = (float*)alloc((size_t)MPAD * 1536 * 4);
    float* qkv_0 = (float*)alloc((size_t)MPAD * 768 * 4);
    u16*   h16_1 = (u16*)alloc((size_t)MPAD * 512 * 2);
    u16*   h16_0 = (u16*)alloc((size_t)MPAD * 256 * 2);
    u16*   om_1  = (u16*)alloc((size_t)MPAD * 512 * 2);
    u16*   om_0  = (u16*)alloc((size_t)MPAD * 256 * 2);
    // ---- fp16 transposed weights ----
    u16* w1T_1   = (u16*)alloc((size_t)512 * 1024 * 2);
    u16* wqkvT_1 = (u16*)alloc((size_t)1536 * 512 * 2);
    u16* w2T_1   = (u16*)alloc((size_t)512 * 512 * 2);
    u16* woT_1   = (u16*)alloc((size_t)512 * 512 * 2);
    u16* w1T_0   = (u16*)alloc((size_t)256 * 512 * 2);
    u16* wqkvT_0 = (u16*)alloc((size_t)768 * 256 * 2);
    u16* w2T_0   = (u16*)alloc((size_t)256 * 256 * 2);
    u16* woT_0   = (u16*)alloc((size_t)256 * 256 * 2);

    // ---- K1: pool + meta + weight transpose + zero everything ----
    PrepP pp;
    pp.fm0 = fm0; pp.fm1 = fm1; pp.kp = kp; pp.ms0 = ms0; pp.ms1 = ms1;
    pp.A1_0 = A1_0; pp.A1_1 = A1_1; pp.A1h_0 = A1h_0; pp.A1h_1 = A1h_1;
    pp.zbase = zbase; pp.out = (float*)d_out;
    int tcum = 0;
    auto setTD = [&](int i, const float* src, u16* dst, int K, int N) {
        pp.td[i].src = src; pp.td[i].dst = dst; pp.td[i].K = K; pp.td[i].N = N;
        pp.td[i].blk0 = tcum; tcum += (K / 64) * (N / 64);
    };
    setTD(0, p1_w1,   w1T_1,   1024, 512);
    setTD(1, a1_wqkv, wqkvT_1, 512, 1536);
    setTD(2, p1_w2,   w2T_1,   512,  512);
    setTD(3, a1_wo,   woT_1,   512,  512);
    setTD(4, p0_w1,   w1T_0,   512,  256);
    setTD(5, a0_wqkv, wqkvT_0, 256,  768);
    setTD(6, p0_w2,   w2T_0,   256,  256);
    setTD(7, a0_wo,   woT_0,   256,  256);
    k1_prep<<<1845, 256, 0, stream>>>(pp);   // 1122 + 560 + 135 + 26 + 2

    // ---- K2: w1 + wqkv GEMMs (split-K=2, atomic into zeroed h/qkv) ----
    GP g2; g2.nd = 4;
    g2.d[0] = { A1h_1, w1T_1,   p1_b1,   h_1,   1024, 512,  1024, 512,  MPAD, 8,  2 };
    g2.d[1] = { A1h_1, wqkvT_1, a1_bqkv, qkv_1, 1024, 1536, 512,  1536, MPAD, 24, 2 };
    g2.d[2] = { A1h_0, w1T_0,   p0_b1,   h_0,   512,  256,  512,  256,  MPAD, 4,  2 };
    g2.d[3] = { A1h_0, wqkvT_0, a0_bqkv, qkv_0, 512,  768,  256,  768,  MPAD, 12, 2 };
    g2.blk0[0] = 0;
    for (int i = 0; i < 4; ++i) g2.blk0[i + 1] = g2.blk0[i] + 9 * g2.d[i].ntiles * g2.d[i].sk;
    gemm_fp16<<<g2.blk0[4], 256, 0, stream>>>(g2);

    // ---- K3: LN+relu->fp16  ||  attention+gates->om fp16 ----
    RP rp;
    rp.h1 = h_1; rp.h0 = h_0; rp.h16_1 = h16_1; rp.h16_0 = h16_0;
    rp.g1 = p1_g; rp.be1 = p1_beta; rp.g0 = p0_g; rp.be0 = p0_beta;
    rp.qkv1 = qkv_1; rp.qkv0 = qkv_0; rp.A1_1 = A1_1; rp.A1_0 = A1_0;
    rp.wg1 = a1_wg; rp.bg1 = a1_bg; rp.wg0 = a0_wg; rp.bg0 = a0_bg;
    rp.om1 = om_1; rp.om0 = om_0;
    k3_rowops<<<2176, 256, 0, stream>>>(rp);

    // ---- K4: w2 + wo GEMMs, two atomic adds into zeroed out ----
    GP g4; g4.nd = 4;
    g4.d[0] = { h16_1, w2T_1, p1_b2, out1, 512, 512, 512, 512, MROW, 8, 1 };
    g4.d[1] = { om_1,  woT_1, a1_bo, out1, 512, 512, 512, 512, MROW, 8, 1 };
    g4.d[2] = { h16_0, w2T_0, p0_b2, out0, 256, 256, 256, 256, MROW, 4, 1 };
    g4.d[3] = { om_0,  woT_0, a0_bo, out0, 256, 256, 256, 256, MROW, 4, 1 };
    g4.blk0[0] = 0;
    for (int i = 0; i < 4; ++i) g4.blk0[i + 1] = g4.blk0[i] + 9 * g4.d[i].ntiles * g4.d[i].sk;
    gemm_fp16<<<g4.blk0[4], 256, 0, stream>>>(g4);
}

// Round 7
// 92.079 us; speedup vs baseline: 4.2749x; 1.1592x over previous
//
#include <hip/hip_runtime.h>
#include <math.h>

#define NKPT 17
#define BATCH 32
#define MROW 544          // BATCH*NKPT
#define MPAD 576          // 9*64

typedef unsigned short u16;
typedef _Float16 half8 __attribute__((ext_vector_type(8)));
typedef float f32x4 __attribute__((ext_vector_type(4)));

__device__ __forceinline__ u16 f2h(float f) {
    _Float16 h = (_Float16)f;
    u16 u; __builtin_memcpy(&u, &h, 2); return u;
}

// ---------------------------------------------------------------- GEMM ----
// BM=64, BN=64, BK=64, 256 threads (4 waves as 2x2 of 32x32), double-buffered
// LDS (one barrier per k-step). A: fp16 [Mpad][lda]. BT: fp16 [N][K].
// dst: f32 atomicAdd (pre-zeroed). sk splits K; bias added by s==0 block.
struct GD {
    const u16* A; const u16* BT; const float* bias; float* dst;
    int lda, ldd, K, N, mstore, ntiles, sk;
};
struct GP { GD d[4]; int blk0[5]; int nd; };

__global__ __launch_bounds__(256) void gemm_fp16(GP P)
{
    __shared__ u16 sA[2][64][72];
    __shared__ u16 sB[2][64][72];
    int bid = blockIdx.x, gi = 0;
    while (gi + 1 < P.nd && bid >= P.blk0[gi + 1]) ++gi;
    const GD g = P.d[gi];
    int local = bid - P.blk0[gi];
    const int nspan = g.ntiles * g.sk;
    const int mt = local / nspan;
    int rem = local - mt * nspan;
    const int nt = rem / g.sk;
    const int s  = rem - nt * g.sk;
    const int m0 = mt * 64, n0 = nt * 64;
    const int Kseg = g.K / g.sk;
    const int kbase = s * Kseg;

    const int t = threadIdx.x;
    const int l = t & 63, w = t >> 6, wr = w >> 1, wc = w & 1;
    const int row = t >> 2, kc = (t & 3) << 4;

    f32x4 acc[2][2];
    #pragma unroll
    for (int i = 0; i < 2; ++i)
        #pragma unroll
        for (int j = 0; j < 2; ++j) { f32x4 z = {0.f,0.f,0.f,0.f}; acc[i][j] = z; }

    const u16* ap = g.A  + (size_t)(m0 + row) * g.lda + kbase + kc;
    const u16* bp = g.BT + (size_t)(n0 + row) * g.K   + kbase + kc;
    uint4 ra0 = *(const uint4*)ap, ra1 = *(const uint4*)(ap + 8);
    uint4 rb0 = *(const uint4*)bp, rb1 = *(const uint4*)(bp + 8);
    *(uint4*)&sA[0][row][kc] = ra0; *(uint4*)&sA[0][row][kc + 8] = ra1;
    *(uint4*)&sB[0][row][kc] = rb0; *(uint4*)&sB[0][row][kc + 8] = rb1;
    __syncthreads();

    int cur = 0;
    for (int k0 = 0; k0 < Kseg; k0 += 64) {
        const bool nxt = (k0 + 64 < Kseg);
        if (nxt) {
            ra0 = *(const uint4*)(ap + k0 + 64); ra1 = *(const uint4*)(ap + k0 + 72);
            rb0 = *(const uint4*)(bp + k0 + 64); rb1 = *(const uint4*)(bp + k0 + 72);
        }
        #pragma unroll
        for (int ks = 0; ks < 64; ks += 32) {
            const int koff = ks + (l >> 4) * 8;
            half8 af0 = *(const half8*)&sA[cur][wr * 32 +      (l & 15)][koff];
            half8 af1 = *(const half8*)&sA[cur][wr * 32 + 16 + (l & 15)][koff];
            half8 bf0 = *(const half8*)&sB[cur][wc * 32 +      (l & 15)][koff];
            half8 bf1 = *(const half8*)&sB[cur][wc * 32 + 16 + (l & 15)][koff];
            acc[0][0] = __builtin_amdgcn_mfma_f32_16x16x32_f16(af0, bf0, acc[0][0], 0, 0, 0);
            acc[0][1] = __builtin_amdgcn_mfma_f32_16x16x32_f16(af0, bf1, acc[0][1], 0, 0, 0);
            acc[1][0] = __builtin_amdgcn_mfma_f32_16x16x32_f16(af1, bf0, acc[1][0], 0, 0, 0);
            acc[1][1] = __builtin_amdgcn_mfma_f32_16x16x32_f16(af1, bf1, acc[1][1], 0, 0, 0);
        }
        if (nxt) {
            int nb = cur ^ 1;
            *(uint4*)&sA[nb][row][kc] = ra0; *(uint4*)&sA[nb][row][kc + 8] = ra1;
            *(uint4*)&sB[nb][row][kc] = rb0; *(uint4*)&sB[nb][row][kc + 8] = rb1;
            __syncthreads();
            cur = nb;
        }
    }

    // D layout: col = l&15, row = (l>>4)*4 + reg  (verified)
    #pragma unroll
    for (int i = 0; i < 2; ++i) {
        #pragma unroll
        for (int j = 0; j < 2; ++j) {
            int col = n0 + wc * 32 + j * 16 + (l & 15);
            float bv = (s == 0) ? g.bias[col] : 0.f;
            #pragma unroll
            for (int rr = 0; rr < 4; ++rr) {
                int m = m0 + wr * 32 + i * 16 + (l >> 4) * 4 + rr;
                if (m < g.mstore)
                    atomicAdd(&g.dst[(size_t)m * g.ldd + col], acc[i][j][rr] + bv);
            }
        }
    }
}

// ---------------------------------------------------------------- prep ----
struct TD { const float* src; u16* dst; int K, N, blk0; };
struct PrepP {
    const float *fm0, *fm1, *kp, *ms0, *ms1;
    const float *wg0, *bg0, *wg1, *bg1;
    u16 *A1h_0, *A1h_1;      // fp16 [MPAD][2C] (GEMM A)
    float *gout0, *gout1;    // [MROW+NKPT][8] sigmoid gates
    char* zbase;             // contiguous zero region (h,qkv,h16,om16)
    float* out;              // d_out base (zeroed here)
    TD td[8];
};

__device__ void zero_chunk(char* base, size_t bytes, int u)
{
    size_t off = (size_t)u * 65536 + (size_t)threadIdx.x * 16;
    #pragma unroll
    for (int r = 0; r < 16; ++r) {
        size_t o = off + (size_t)r * 4096;
        if (o + 16 <= bytes) *(float4*)(base + o) = make_float4(0.f, 0.f, 0.f, 0.f);
    }
}

// 8 heads x 32 lanes: gate_h = sigmoid(sx . wg[:,h] + bg[h])
__device__ void gates_from_sx(const float* sx, int C, const float* wg,
                              const float* bg, float* gout8)
{
    int t = threadIdx.x;
    int h = t >> 5, e = t & 31;
    float a = 0.f;
    for (int c = e; c < C; c += 32) a += sx[c] * wg[c * 8 + h];
    a += __shfl_xor(a, 16, 32); a += __shfl_xor(a, 8, 32);
    a += __shfl_xor(a, 4, 32);  a += __shfl_xor(a, 2, 32);
    a += __shfl_xor(a, 1, 32);
    if (e == 0) gout8[h] = 1.0f / (1.0f + expf(-(a + bg[h])));
}

// Coalesced pool: 32-lane group per channel; lanes 0..24 = window elements.
template<int C, int H, int W>
__device__ void pool_row(int b, int n, const float* fm, const float* kp,
                         const float* ms, u16* A1h, const float* wg,
                         const float* bg, float* gout, float* sx)
{
    const int t = threadIdx.x;   // 256
    const int e = t & 31, grp = t >> 5;   // 8 channel-groups
    float kx = kp[(b * NKPT + n) * 2 + 0];
    float ky = kp[(b * NKPT + n) * 2 + 1];
    int cx = (int)rintf(kx * ((float)W / 192.0f));   // RNE == jnp.round
    int cy = (int)rintf(ky * ((float)H / 256.0f));
    int dy = e / 5, dx = e % 5;
    float wgt = 0.f; int off = 0;
    if (e < 25) {
        int iy = min(max(cy + dy - 2, 0), H - 1);
        int ix = min(max(cx + dx - 2, 0), W - 1);
        off = iy * W + ix;
        wgt = expf(-(float)((dy - 2) * (dy - 2) + (dx - 2) * (dx - 2)) / 8.0f);
    }
    float ws_ = wgt;
    ws_ += __shfl_xor(ws_, 16, 32); ws_ += __shfl_xor(ws_, 8, 32);
    ws_ += __shfl_xor(ws_, 4, 32);  ws_ += __shfl_xor(ws_, 2, 32);
    ws_ += __shfl_xor(ws_, 1, 32);
    const float inv = 1.0f / ws_;

    const size_t plane = (size_t)H * W;
    const float* pf = fm + ((size_t)b * C + grp) * plane + off;
    #pragma unroll 4
    for (int c0 = grp; c0 < C; c0 += 8, pf += 8 * plane) {
        float v = 0.f;
        if (e < 25) v = wgt * (*pf);
        v += __shfl_xor(v, 16, 32); v += __shfl_xor(v, 8, 32);
        v += __shfl_xor(v, 4, 32);  v += __shfl_xor(v, 2, 32);
        v += __shfl_xor(v, 1, 32);
        if (e == 0) sx[c0] = v * inv;
    }
    __syncthreads();
    u16* rowh = A1h + (size_t)(b * NKPT + n) * (2 * C);
    for (int c = t; c < C; c += 256) {
        rowh[c] = f2h(sx[c]);
        rowh[C + c] = f2h(ms[n * C + c]);
    }
    gates_from_sx(sx, C, wg, bg, gout + (size_t)(b * NKPT + n) * 8);
}

template<int C>
__device__ void meta_row(int n, const float* ms, u16* A1h, const float* wg,
                         const float* bg, float* gout, float* sx)
{
    const int t = threadIdx.x;
    u16* rowh = A1h + (size_t)(MROW + n) * (2 * C);
    for (int c = t; c < C; c += 256) {
        float v = ms[n * C + c];
        sx[c] = v;
        rowh[c] = f2h(v);
        rowh[C + c] = 0;
    }
    __syncthreads();
    gates_from_sx(sx, C, wg, bg, gout + (size_t)(MROW + n) * 8);
}

__device__ void wtrans_tile(const TD& d, int u, float* sT)  // sT: [64][65] f32
{
    const int ntx = d.N >> 6;
    const int tk = u / ntx, tn = u % ntx;
    const int k0 = tk << 6, n0 = tn << 6;
    const int t = threadIdx.x;
    {
        int r = t >> 2, cq = (t & 3) << 4;
        const float* sp = d.src + (size_t)(k0 + r) * d.N + n0 + cq;
        #pragma unroll
        for (int i = 0; i < 4; ++i) {
            float4 v = *(const float4*)(sp + 4 * i);
            sT[r * 65 + cq + 4 * i + 0] = v.x;
            sT[r * 65 + cq + 4 * i + 1] = v.y;
            sT[r * 65 + cq + 4 * i + 2] = v.z;
            sT[r * 65 + cq + 4 * i + 3] = v.w;
        }
    }
    __syncthreads();
    {
        int nn = t >> 2, kq = (t & 3) << 4;
        u16 hv[16] __attribute__((aligned(16)));
        #pragma unroll
        for (int i = 0; i < 16; ++i) hv[i] = f2h(sT[(kq + i) * 65 + nn]);
        u16* dp = d.dst + (size_t)(n0 + nn) * d.K + k0 + kq;
        *reinterpret_cast<uint4*>(dp) = *reinterpret_cast<uint4*>(&hv[0]);
        *reinterpret_cast<uint4*>(dp + 8) = *reinterpret_cast<uint4*>(&hv[8]);
    }
}

__global__ __launch_bounds__(256) void k1_prep(PrepP P)
{
    __shared__ float ps[64 * 65];
    int bid = blockIdx.x;
    if (bid < 1088) {
        if (bid < 544) pool_row<512, 48, 36>(bid / NKPT, bid % NKPT, P.fm1, P.kp, P.ms1, P.A1h_1, P.wg1, P.bg1, P.gout1, ps);
        else { int r = bid - 544; pool_row<256, 96, 72>(r / NKPT, r % NKPT, P.fm0, P.kp, P.ms0, P.A1h_0, P.wg0, P.bg0, P.gout0, ps); }
    } else if (bid < 1122) {
        int u = bid - 1088;
        if (u < NKPT) meta_row<512>(u, P.ms1, P.A1h_1, P.wg1, P.bg1, P.gout1, ps);
        else          meta_row<256>(u - NKPT, P.ms0, P.A1h_0, P.wg0, P.bg0, P.gout0, ps);
    } else if (bid < 1682) {
        int u = bid - 1122, i = 0;
        while (i + 1 < 8 && u >= P.td[i + 1].blk0) ++i;
        wtrans_tile(P.td[i], u - P.td[i].blk0, ps);
    } else if (bid < 1817) {
        zero_chunk(P.zbase, 8847360, bid - 1682);
    } else if (bid < 1843) {
        zero_chunk((char*)P.out, (size_t)417792 * 4, bid - 1817);
    } else if (bid == 1843) {
        zero_chunk((char*)(P.A1h_1 + (size_t)561 * 1024), 30720, 0);
    } else {
        zero_chunk((char*)(P.A1h_0 + (size_t)561 * 512), 15360, 0);
    }
}

// ----------------------------------------------- rowops: LN+relu / attn ---
template<int C>
__device__ void attn_row(int r, const float* qkv, const float* gout,
                         u16* om, float* sred)
{
    constexpr int D = C / 8;
    constexpr int TC = 3 * C;
    const int t = threadIdx.x;
    const int n = r % NKPT;
    const float* row  = qkv + (size_t)r * TC;
    const float* mrow = qkv + (size_t)(MROW + n) * TC;
    {
        int dot = t >> 3, sub = t & 7;           // 32 dots x 8 threads
        int p = dot >> 3, h = dot & 7;
        const float* q = (p & 2) ? mrow : row;
        const float* k = ((p & 1) ? mrow : row) + C;
        float a = 0.f;
        int base = h * D + sub * (D / 8);
        #pragma unroll
        for (int i = 0; i < D / 8; ++i) a += q[base + i] * k[base + i];
        a += __shfl_xor(a, 4, 8); a += __shfl_xor(a, 2, 8); a += __shfl_xor(a, 1, 8);
        if (sub == 0) sred[dot] = a;
    }
    if (t >= 32 && t < 40) sred[32 + (t - 32)] = gout[(size_t)r * 8 + (t - 32)];
    else if (t >= 40 && t < 48) sred[32 + (t - 32)] = gout[(size_t)(MROW + n) * 8 + (t - 40)];
    __syncthreads();
    if (t < 8) {
        int h = t;
        float scale = (float)(1.0 / sqrt((double)D));
        float c0 = 0.f, c1 = 0.f;
        #pragma unroll
        for (int s = 0; s < 2; ++s) {
            float a0 = sred[(2 * s) * 8 + h] * scale;
            float a1 = sred[(2 * s + 1) * 8 + h] * scale;
            float mx = fmaxf(a0, a1);
            float e0 = expf(a0 - mx), e1 = expf(a1 - mx);
            float inv = 1.0f / (e0 + e1);
            float gt = sred[32 + s * 8 + h];
            c0 += e0 * inv * gt;
            c1 += e1 * inv * gt;
        }
        sred[48 + h] = 0.5f * c0;
        sred[56 + h] = 0.5f * c1;
    }
    __syncthreads();
    const float* v0 = row + 2 * C;
    const float* v1 = mrow + 2 * C;
    for (int c = t; c < C; c += 256) {
        int h = c / D;
        om[(size_t)r * C + c] = f2h(sred[48 + h] * v0[c] + sred[56 + h] * v1[c]);
    }
}

struct RP {
    const float *h1, *h0; u16 *h16_1, *h16_0;
    const float *g1, *be1, *g0, *be0;
    const float *qkv1, *qkv0;
    const float *gout1, *gout0;
    u16 *om1, *om0;
};
__global__ __launch_bounds__(256) void k3_rowops(RP P)
{
    __shared__ float sh[64];
    int bid = blockIdx.x;
    if (bid < 1088) {
        int lvl1 = bid < 544;
        int r = lvl1 ? bid : bid - 544;
        int C = lvl1 ? 512 : 256;
        const float* h = (lvl1 ? P.h1 : P.h0) + (size_t)r * C;
        u16* h16 = (lvl1 ? P.h16_1 : P.h16_0) + (size_t)r * C;
        const float* gg = lvl1 ? P.g1 : P.g0;
        const float* bb = lvl1 ? P.be1 : P.be0;
        int t = threadIdx.x;
        int nc = C >> 8;
        float v[2] = {0.f, 0.f};
        float s1 = 0.f, s2 = 0.f;
        for (int i = 0; i < nc; ++i) { float x = h[t + (i << 8)]; v[i] = x; s1 += x; s2 += x * x; }
        #pragma unroll
        for (int o = 32; o > 0; o >>= 1) { s1 += __shfl_down(s1, o); s2 += __shfl_down(s2, o); }
        int lane = t & 63, wv = t >> 6;
        if (lane == 0) { sh[wv * 2] = s1; sh[wv * 2 + 1] = s2; }
        __syncthreads();
        if (t == 0) {
            float a = 0.f, b = 0.f;
            #pragma unroll
            for (int q = 0; q < 4; ++q) { a += sh[q * 2]; b += sh[q * 2 + 1]; }
            float m = a / (float)C;
            float var = b / (float)C - m * m;
            sh[8] = m; sh[9] = 1.0f / sqrtf(var + 1e-5f);
        }
        __syncthreads();
        float m = sh[8], rs = sh[9];
        for (int i = 0; i < nc; ++i) {
            int c = t + (i << 8);
            float x = (v[i] - m) * rs * gg[c] + bb[c];
            h16[c] = f2h(fmaxf(x, 0.f));
        }
    } else {
        int a = bid - 1088;
        if (a < 544) attn_row<512>(a, P.qkv1, P.gout1, P.om1, sh);
        else         attn_row<256>(a - 544, P.qkv0, P.gout0, P.om0, sh);
    }
}

// --------------------------------------------- fallback (round-2 kernel) --
template<int C, int H, int W>
__global__ __launch_bounds__(C) void fb_level(
    const float* __restrict__ fm, const float* __restrict__ kp,
    const float* __restrict__ ms, const float* __restrict__ w1,
    const float* __restrict__ b1, const float* __restrict__ gvec,
    const float* __restrict__ beta, const float* __restrict__ w2,
    const float* __restrict__ b2, const float* __restrict__ wqkv,
    const float* __restrict__ bqkv, const float* __restrict__ wg,
    const float* __restrict__ bg, const float* __restrict__ wo,
    const float* __restrict__ bo, float* __restrict__ out)
{
    constexpr int D = C / 8;
    constexpr int NW = C / 64;
    __shared__ float x0[C], x1[C], hbuf[C];
    __shared__ float q0[C], k0[C], v0[C], q1[C], k1[C], v1[C];
    __shared__ float om[C];
    __shared__ float gw[25];
    __shared__ float gwsum_inv;
    __shared__ float redA[NW], redB[NW];
    __shared__ float stats[2];
    __shared__ float gates[2][8];
    __shared__ float att[2][2][8];
    const int j = threadIdx.x;
    const int blk = blockIdx.x;
    const int b = blk / NKPT, n = blk % NKPT;
    if (j < 25) { int dy = j / 5 - 2, dx = j % 5 - 2; gw[j] = expf(-(float)(dy*dy+dx*dx) / 8.0f); }
    __syncthreads();
    if (j == 0) { float s = 0.f; for (int t2 = 0; t2 < 25; ++t2) s += gw[t2]; gwsum_inv = 1.0f / s; }
    float kx = kp[(b * NKPT + n) * 2 + 0];
    float ky = kp[(b * NKPT + n) * 2 + 1];
    int cx = (int)rintf(kx * ((float)W / 192.0f));
    int cy = (int)rintf(ky * ((float)H / 256.0f));
    int ix[5], iy[5];
    #pragma unroll
    for (int t2 = 0; t2 < 5; ++t2) {
        ix[t2] = min(max(cx + t2 - 2, 0), W - 1);
        iy[t2] = min(max(cy + t2 - 2, 0), H - 1);
    }
    __syncthreads();
    {
        const float* fmb = fm + ((size_t)b * C + j) * (H * W);
        float acc = 0.f;
        #pragma unroll
        for (int yy = 0; yy < 5; ++yy) {
            const float* row = fmb + iy[yy] * W;
            #pragma unroll
            for (int xx = 0; xx < 5; ++xx) acc += gw[yy * 5 + xx] * row[ix[xx]];
        }
        x0[j] = acc * gwsum_inv;
        x1[j] = ms[n * C + j];
    }
    __syncthreads();
    float hacc = b1[j];
    for (int i = 0; i < C; ++i) hacc += x0[i] * w1[i * C + j];
    for (int i = 0; i < C; ++i) hacc += x1[i] * w1[(C + i) * C + j];
    {
        float s1 = hacc, s2 = hacc * hacc;
        #pragma unroll
        for (int o = 32; o > 0; o >>= 1) { s1 += __shfl_down(s1, o); s2 += __shfl_down(s2, o); }
        int lane = j & 63, wid = j >> 6;
        if (lane == 0) { redA[wid] = s1; redB[wid] = s2; }
        __syncthreads();
        if (j == 0) {
            float t1 = 0.f, t2 = 0.f;
            for (int w = 0; w < NW; ++w) { t1 += redA[w]; t2 += redB[w]; }
            float m = t1 / (float)C, v = t2 / (float)C - m * m;
            stats[0] = m; stats[1] = 1.0f / sqrtf(v + 1e-5f);
        }
        __syncthreads();
    }
    hbuf[j] = fmaxf((hacc - stats[0]) * stats[1] * gvec[j] + beta[j], 0.f);
    __syncthreads();
    float pj = b2[j];
    for (int i = 0; i < C; ++i) pj += hbuf[i] * w2[i * C + j];
    {
        float aq0 = bqkv[j], ak0 = bqkv[C + j], av0 = bqkv[2 * C + j];
        float aq1 = aq0, ak1 = ak0, av1 = av0;
        for (int i = 0; i < C; ++i) {
            float xi0 = x0[i], xi1 = x1[i];
            const float* wr = wqkv + (size_t)i * (3 * C);
            float wq = wr[j], wk = wr[C + j], wv = wr[2 * C + j];
            aq0 += xi0 * wq; aq1 += xi1 * wq;
            ak0 += xi0 * wk; ak1 += xi1 * wk;
            av0 += xi0 * wv; av1 += xi1 * wv;
        }
        q0[j] = aq0; k0[j] = ak0; v0[j] = av0;
        q1[j] = aq1; k1[j] = ak1; v1[j] = av1;
    }
    __syncthreads();
    if (j < 16) {
        int s = j >> 3, hh = j & 7;
        const float* xs = s ? x1 : x0;
        float a = bg[hh];
        for (int i = 0; i < C; ++i) a += xs[i] * wg[i * 8 + hh];
        gates[s][hh] = 1.0f / (1.0f + expf(-a));
    }
    if (j < 32) {
        int hh = j >> 2, st = j & 3;
        const float* qs = (st & 2) ? q1 : q0;
        const float* kt = (st & 1) ? k1 : k0;
        float a = 0.f;
        for (int i = hh * D; i < (hh + 1) * D; ++i) a += qs[i] * kt[i];
        att[(st >> 1)][st & 1][hh] = a;
    }
    __syncthreads();
    if (j < 16) {
        int s = j >> 3, hh = j & 7;
        const float inv = 1.0f / sqrtf((float)D);
        float a0 = att[s][0][hh] * inv, a1 = att[s][1][hh] * inv;
        float mx = fmaxf(a0, a1);
        float e0 = expf(a0 - mx), e1 = expf(a1 - mx);
        float den = e0 + e1;
        att[s][0][hh] = e0 / den; att[s][1][hh] = e1 / den;
    }
    __syncthreads();
    {
        int hh = j / D;
        float o0 = (att[0][0][hh] * v0[j] + att[0][1][hh] * v1[j]) * gates[0][hh];
        float o1 = (att[1][0][hh] * v0[j] + att[1][1][hh] * v1[j]) * gates[1][hh];
        om[j] = 0.5f * (o0 + o1);
    }
    __syncthreads();
    float oacc = bo[j];
    for (int i = 0; i < C; ++i) oacc += om[i] * wo[i * C + j];
    out[((size_t)b * NKPT + n) * C + j] = oacc + pj;
}

// ------------------------------------------------------------- launch -----
extern "C" void kernel_launch(void* const* d_in, const int* in_sizes, int n_in,
                              void* d_out, int out_size, void* d_ws, size_t ws_size,
                              hipStream_t stream) {
    (void)in_sizes; (void)n_in; (void)out_size;
    const float* fm0  = (const float*)d_in[0];
    const float* fm1  = (const float*)d_in[1];
    const float* kp   = (const float*)d_in[2];
    const float* ms0     = (const float*)d_in[3];
    const float* p0_w1   = (const float*)d_in[4];
    const float* p0_b1   = (const float*)d_in[5];
    const float* p0_g    = (const float*)d_in[6];
    const float* p0_beta = (const float*)d_in[7];
    const float* p0_w2   = (const float*)d_in[8];
    const float* p0_b2   = (const float*)d_in[9];
    const float* a0_wqkv = (const float*)d_in[10];
    const float* a0_bqkv = (const float*)d_in[11];
    const float* a0_wg   = (const float*)d_in[12];
    const float* a0_bg   = (const float*)d_in[13];
    const float* a0_wo   = (const float*)d_in[14];
    const float* a0_bo   = (const float*)d_in[15];
    const float* ms1     = (const float*)d_in[16];
    const float* p1_w1   = (const float*)d_in[17];
    const float* p1_b1   = (const float*)d_in[18];
    const float* p1_g    = (const float*)d_in[19];
    const float* p1_beta = (const float*)d_in[20];
    const float* p1_w2   = (const float*)d_in[21];
    const float* p1_b2   = (const float*)d_in[22];
    const float* a1_wqkv = (const float*)d_in[23];
    const float* a1_bqkv = (const float*)d_in[24];
    const float* a1_wg   = (const float*)d_in[25];
    const float* a1_bg   = (const float*)d_in[26];
    const float* a1_wo   = (const float*)d_in[27];
    const float* a1_bo   = (const float*)d_in[28];

    float* out0 = (float*)d_out;                               // (544,256)
    float* out1 = (float*)d_out + (size_t)MROW * 256;          // (544,512)

    const size_t WS_NEED = 15240704;
    if (ws_size < WS_NEED || d_ws == nullptr) {
        fb_level<256, 96, 72><<<MROW, 256, 0, stream>>>(
            fm0, kp, ms0, p0_w1, p0_b1, p0_g, p0_beta, p0_w2, p0_b2,
            a0_wqkv, a0_bqkv, a0_wg, a0_bg, a0_wo, a0_bo, out0);
        fb_level<512, 48, 36><<<MROW, 512, 0, stream>>>(
            fm1, kp, ms1, p1_w1, p1_b1, p1_g, p1_beta, p1_w2, p1_b2,
            a1_wqkv, a1_bqkv, a1_wg, a1_bg, a1_wo, a1_bo, out1);
        return;
    }

    char* cur = (char*)d_ws;
    auto alloc = [&](size_t bytes) { char* p = cur; cur += (bytes + 255) & ~(size_t)255; return p; };
    u16*   A1h_1 = (u16*)alloc((size_t)MPAD * 1024 * 2);
    u16*   A1h_0 = (u16*)alloc((size_t)MPAD * 512 * 2);
    // ---- contiguous zero region (8,847,360 B) ----
    char*  zbase = cur;
    float* h_1   = (float*)alloc((size_t)MPAD * 512 * 4);
    float* h_0   = (float*)alloc((size_t)MPAD * 256 * 4);
    float* qkv_1 = (float*)alloc((size_t)MPAD * 1536 * 4);
    float* qkv_0 = (float*)alloc((size_t)MPAD * 768 * 4);
    u16*   h16_1 = (u16*)alloc((size_t)MPAD * 512 * 2);
    u16*   h16_0 = (u16*)alloc((size_t)MPAD * 256 * 2);
    u16*   om_1  = (u16*)alloc((size_t)MPAD * 512 * 2);
    u16*   om_0  = (u16*)alloc((size_t)MPAD * 256 * 2);
    // ---- fp16 transposed weights ----
    u16* w1T_1   = (u16*)alloc((size_t)512 * 1024 * 2);
    u16* wqkvT_1 = (u16*)alloc((size_t)1536 * 512 * 2);
    u16* w2T_1   = (u16*)alloc((size_t)512 * 512 * 2);
    u16* woT_1   = (u16*)alloc((size_t)512 * 512 * 2);
    u16* w1T_0   = (u16*)alloc((size_t)256 * 512 * 2);
    u16* wqkvT_0 = (u16*)alloc((size_t)768 * 256 * 2);
    u16* w2T_0   = (u16*)alloc((size_t)256 * 256 * 2);
    u16* woT_0   = (u16*)alloc((size_t)256 * 256 * 2);
    float* gout1 = (float*)alloc((size_t)(MROW + NKPT) * 8 * 4);
    float* gout0 = (float*)alloc((size_t)(MROW + NKPT) * 8 * 4);

    // ---- K1: pool(+gates) + meta + weight transpose + zero everything ----
    PrepP pp;
    pp.fm0 = fm0; pp.fm1 = fm1; pp.kp = kp; pp.ms0 = ms0; pp.ms1 = ms1;
    pp.wg0 = a0_wg; pp.bg0 = a0_bg; pp.wg1 = a1_wg; pp.bg1 = a1_bg;
    pp.A1h_0 = A1h_0; pp.A1h_1 = A1h_1;
    pp.gout0 = gout0; pp.gout1 = gout1;
    pp.zbase = zbase; pp.out = (float*)d_out;
    int tcum = 0;
    auto setTD = [&](int i, const float* src, u16* dst, int K, int N) {
        pp.td[i].src = src; pp.td[i].dst = dst; pp.td[i].K = K; pp.td[i].N = N;
        pp.td[i].blk0 = tcum; tcum += (K / 64) * (N / 64);
    };
    setTD(0, p1_w1,   w1T_1,   1024, 512);
    setTD(1, a1_wqkv, wqkvT_1, 512, 1536);
    setTD(2, p1_w2,   w2T_1,   512,  512);
    setTD(3, a1_wo,   woT_1,   512,  512);
    setTD(4, p0_w1,   w1T_0,   512,  256);
    setTD(5, a0_wqkv, wqkvT_0, 256,  768);
    setTD(6, p0_w2,   w2T_0,   256,  256);
    setTD(7, a0_wo,   woT_0,   256,  256);
    k1_prep<<<1845, 256, 0, stream>>>(pp);

    // ---- K2: w1 + wqkv GEMMs (split-K=2, atomic into zeroed h/qkv) ----
    GP g2; g2.nd = 4;
    g2.d[0] = { A1h_1, w1T_1,   p1_b1,   h_1,   1024, 512,  1024, 512,  MPAD, 8,  2 };
    g2.d[1] = { A1h_1, wqkvT_1, a1_bqkv, qkv_1, 1024, 1536, 512,  1536, MPAD, 24, 2 };
    g2.d[2] = { A1h_0, w1T_0,   p0_b1,   h_0,   512,  256,  512,  256,  MPAD, 4,  2 };
    g2.d[3] = { A1h_0, wqkvT_0, a0_bqkv, qkv_0, 512,  768,  256,  768,  MPAD, 12, 2 };
    g2.blk0[0] = 0;
    for (int i = 0; i < 4; ++i) g2.blk0[i + 1] = g2.blk0[i] + 9 * g2.d[i].ntiles * g2.d[i].sk;
    gemm_fp16<<<g2.blk0[4], 256, 0, stream>>>(g2);

    // ---- K3: LN+relu->fp16  ||  attention (precomputed gates) ----
    RP rp;
    rp.h1 = h_1; rp.h0 = h_0; rp.h16_1 = h16_1; rp.h16_0 = h16_0;
    rp.g1 = p1_g; rp.be1 = p1_beta; rp.g0 = p0_g; rp.be0 = p0_beta;
    rp.qkv1 = qkv_1; rp.qkv0 = qkv_0;
    rp.gout1 = gout1; rp.gout0 = gout0;
    rp.om1 = om_1; rp.om0 = om_0;
    k3_rowops<<<2176, 256, 0, stream>>>(rp);

    // ---- K4: w2 + wo GEMMs, two atomic adds into zeroed out ----
    GP g4; g4.nd = 4;
    g4.d[0] = { h16_1, w2T_1, p1_b2, out1, 512, 512, 512, 512, MROW, 8, 1 };
    g4.d[1] = { om_1,  woT_1, a1_bo, out1, 512, 512, 512, 512, MROW, 8, 1 };
    g4.d[2] = { h16_0, w2T_0, p0_b2, out0, 256, 256, 256, 256, MROW, 4, 1 };
    g4.d[3] = { om_0,  woT_0, a0_bo, out0, 256, 256, 256, 256, MROW, 4, 1 };
    g4.blk0[0] = 0;
    for (int i = 0; i < 4; ++i) g4.blk0[i + 1] = g4.blk0[i] + 9 * g4.d[i].ntiles * g4.d[i].sk;
    gemm_fp16<<<g4.blk0[4], 256, 0, stream>>>(g4);
}

// Round 8
// 82.660 us; speedup vs baseline: 4.7620x; 1.1139x over previous
//
#include <hip/hip_runtime.h>
#include <math.h>

#define NKPT 17
#define BATCH 32
#define MROW 544          // BATCH*NKPT
#define MPAD 576          // 9*64

typedef unsigned short u16;
typedef _Float16 half8 __attribute__((ext_vector_type(8)));
typedef float f32x4 __attribute__((ext_vector_type(4)));

__device__ __forceinline__ u16 f2h(float f) {
    _Float16 h = (_Float16)f;
    u16 u; __builtin_memcpy(&u, &h, 2); return u;
}
__device__ __forceinline__ float h2f(u16 u) {
    _Float16 h; __builtin_memcpy(&h, &u, 2); return (float)h;
}

// ------------------------------------------------- GEMM -> fp16 parts -----
// BM=64, BN=64, BK=64, 256 threads (4 waves as 2x2 of 32x32), double-buffered
// LDS, one barrier per k-step. A: fp16 [MPAD][lda]. BT: fp16 [N][K].
// Split-K: part s stores DIRECTLY (fp16) to dst + s*MPAD*ldd. No atomics.
struct GDp {
    const u16* A; const u16* BT; const float* bias; u16* dst;
    int lda, ldd, K, N, ntiles, sk;
};
struct GPp { GDp d[4]; int blk0[5]; int nd; };

__global__ __launch_bounds__(256) void gemm_part(GPp P)
{
    __shared__ u16 sA[2][64][72];
    __shared__ u16 sB[2][64][72];
    int bid = blockIdx.x, gi = 0;
    while (gi + 1 < P.nd && bid >= P.blk0[gi + 1]) ++gi;
    const GDp g = P.d[gi];
    int local = bid - P.blk0[gi];
    const int nspan = g.ntiles * g.sk;
    const int mt = local / nspan;
    int rem = local - mt * nspan;
    const int nt = rem / g.sk;
    const int s  = rem - nt * g.sk;
    const int m0 = mt * 64, n0 = nt * 64;
    const int Kseg = g.K / g.sk;
    const int kbase = s * Kseg;

    const int t = threadIdx.x;
    const int l = t & 63, w = t >> 6, wr = w >> 1, wc = w & 1;
    const int row = t >> 2, kc = (t & 3) << 4;

    f32x4 acc[2][2];
    #pragma unroll
    for (int i = 0; i < 2; ++i)
        #pragma unroll
        for (int j = 0; j < 2; ++j) { f32x4 z = {0.f,0.f,0.f,0.f}; acc[i][j] = z; }

    const u16* ap = g.A  + (size_t)(m0 + row) * g.lda + kbase + kc;
    const u16* bp = g.BT + (size_t)(n0 + row) * g.K   + kbase + kc;
    uint4 ra0 = *(const uint4*)ap, ra1 = *(const uint4*)(ap + 8);
    uint4 rb0 = *(const uint4*)bp, rb1 = *(const uint4*)(bp + 8);
    *(uint4*)&sA[0][row][kc] = ra0; *(uint4*)&sA[0][row][kc + 8] = ra1;
    *(uint4*)&sB[0][row][kc] = rb0; *(uint4*)&sB[0][row][kc + 8] = rb1;
    __syncthreads();

    int cur = 0;
    for (int k0 = 0; k0 < Kseg; k0 += 64) {
        const bool nxt = (k0 + 64 < Kseg);
        if (nxt) {
            ra0 = *(const uint4*)(ap + k0 + 64); ra1 = *(const uint4*)(ap + k0 + 72);
            rb0 = *(const uint4*)(bp + k0 + 64); rb1 = *(const uint4*)(bp + k0 + 72);
        }
        #pragma unroll
        for (int ks = 0; ks < 64; ks += 32) {
            const int koff = ks + (l >> 4) * 8;
            half8 af0 = *(const half8*)&sA[cur][wr * 32 +      (l & 15)][koff];
            half8 af1 = *(const half8*)&sA[cur][wr * 32 + 16 + (l & 15)][koff];
            half8 bf0 = *(const half8*)&sB[cur][wc * 32 +      (l & 15)][koff];
            half8 bf1 = *(const half8*)&sB[cur][wc * 32 + 16 + (l & 15)][koff];
            acc[0][0] = __builtin_amdgcn_mfma_f32_16x16x32_f16(af0, bf0, acc[0][0], 0, 0, 0);
            acc[0][1] = __builtin_amdgcn_mfma_f32_16x16x32_f16(af0, bf1, acc[0][1], 0, 0, 0);
            acc[1][0] = __builtin_amdgcn_mfma_f32_16x16x32_f16(af1, bf0, acc[1][0], 0, 0, 0);
            acc[1][1] = __builtin_amdgcn_mfma_f32_16x16x32_f16(af1, bf1, acc[1][1], 0, 0, 0);
        }
        if (nxt) {
            int nb = cur ^ 1;
            *(uint4*)&sA[nb][row][kc] = ra0; *(uint4*)&sA[nb][row][kc + 8] = ra1;
            *(uint4*)&sB[nb][row][kc] = rb0; *(uint4*)&sB[nb][row][kc + 8] = rb1;
            __syncthreads();
            cur = nb;
        }
    }

    // D layout: col = l&15, row = (l>>4)*4 + reg (verified). Direct fp16 store.
    u16* dbase = g.dst + (size_t)s * MPAD * g.ldd;
    #pragma unroll
    for (int i = 0; i < 2; ++i) {
        #pragma unroll
        for (int j = 0; j < 2; ++j) {
            int col = n0 + wc * 32 + j * 16 + (l & 15);
            float bv = (s == 0) ? g.bias[col] : 0.f;
            #pragma unroll
            for (int rr = 0; rr < 4; ++rr) {
                int m = m0 + wr * 32 + i * 16 + (l >> 4) * 4 + rr;
                dbase[(size_t)m * g.ldd + col] = f2h(acc[i][j][rr] + bv);
            }
        }
    }
}

// ------------------------------------------------- GEMM -> f32 out --------
// BM=32, BN=64, BK=64. A: fp16 [MPAD][K]. BT: fp16 [N][K]. Direct f32 store.
struct GDo {
    const u16* A; const u16* BT; const float* bias; float* dst;
    int lda, ldd, K, N, mstore, ntiles;
};
struct GPo { GDo d[2]; int blk0[3]; int nd; };

__global__ __launch_bounds__(256) void gemm_out(GPo P)
{
    __shared__ u16 sA[2][32][72];
    __shared__ u16 sB[2][64][72];
    int bid = blockIdx.x, gi = 0;
    while (gi + 1 < P.nd && bid >= P.blk0[gi + 1]) ++gi;
    const GDo g = P.d[gi];
    int local = bid - P.blk0[gi];
    const int mt = local / g.ntiles, nt = local % g.ntiles;
    const int m0 = mt * 32, n0 = nt * 64;

    const int t = threadIdx.x;
    const int l = t & 63, w = t >> 6, wr = w >> 1, wc = w & 1;
    const int rowA = t >> 3, kcA = (t & 7) << 3;   // 32 rows x 8 el
    const int rowB = t >> 2, kcB = (t & 3) << 4;   // 64 rows x 16 el

    f32x4 acc[2];
    { f32x4 z = {0.f,0.f,0.f,0.f}; acc[0] = z; acc[1] = z; }

    const u16* ap = g.A  + (size_t)(m0 + rowA) * g.lda + kcA;
    const u16* bp = g.BT + (size_t)(n0 + rowB) * g.K   + kcB;
    uint4 ra  = *(const uint4*)ap;
    uint4 rb0 = *(const uint4*)bp, rb1 = *(const uint4*)(bp + 8);
    *(uint4*)&sA[0][rowA][kcA] = ra;
    *(uint4*)&sB[0][rowB][kcB] = rb0; *(uint4*)&sB[0][rowB][kcB + 8] = rb1;
    __syncthreads();

    int cur = 0;
    for (int k0 = 0; k0 < g.K; k0 += 64) {
        const bool nxt = (k0 + 64 < g.K);
        if (nxt) {
            ra  = *(const uint4*)(ap + k0 + 64);
            rb0 = *(const uint4*)(bp + k0 + 64); rb1 = *(const uint4*)(bp + k0 + 72);
        }
        #pragma unroll
        for (int ks = 0; ks < 64; ks += 32) {
            const int koff = ks + (l >> 4) * 8;
            half8 af  = *(const half8*)&sA[cur][wr * 16 + (l & 15)][koff];
            half8 bf0 = *(const half8*)&sB[cur][wc * 32 +      (l & 15)][koff];
            half8 bf1 = *(const half8*)&sB[cur][wc * 32 + 16 + (l & 15)][koff];
            acc[0] = __builtin_amdgcn_mfma_f32_16x16x32_f16(af, bf0, acc[0], 0, 0, 0);
            acc[1] = __builtin_amdgcn_mfma_f32_16x16x32_f16(af, bf1, acc[1], 0, 0, 0);
        }
        if (nxt) {
            int nb = cur ^ 1;
            *(uint4*)&sA[nb][rowA][kcA] = ra;
            *(uint4*)&sB[nb][rowB][kcB] = rb0; *(uint4*)&sB[nb][rowB][kcB + 8] = rb1;
            __syncthreads();
            cur = nb;
        }
    }

    #pragma unroll
    for (int j = 0; j < 2; ++j) {
        int col = n0 + wc * 32 + j * 16 + (l & 15);
        float bv = g.bias[col];
        #pragma unroll
        for (int rr = 0; rr < 4; ++rr) {
            int m = m0 + wr * 16 + (l >> 4) * 4 + rr;
            if (m < g.mstore)
                g.dst[(size_t)m * g.ldd + col] = acc[j][rr] + bv;
        }
    }
}

// ---------------------------------------------------------------- prep ----
struct TD { const float* src; u16* dst; int K, N, ld, koff, blk0; };
struct PrepP {
    const float *fm0, *fm1, *kp, *ms0, *ms1;
    const float *wg0, *bg0, *wg1, *bg1;
    const float *b2_1, *bo_1, *b2_0, *bo_0;
    u16 *A1h_0, *A1h_1;      // fp16 [MPAD][2C] (GEMM A)
    float *gout0, *gout1;    // [MROW+NKPT][8] sigmoid gates
    float *bsum1, *bsum0;    // b2+bo per level
    TD td[8];
};

// 8 heads x 32 lanes: gate_h = sigmoid(sx . wg[:,h] + bg[h])
__device__ void gates_from_sx(const float* sx, int C, const float* wg,
                              const float* bg, float* gout8)
{
    int t = threadIdx.x;
    int h = t >> 5, e = t & 31;
    float a = 0.f;
    for (int c = e; c < C; c += 32) a += sx[c] * wg[c * 8 + h];
    a += __shfl_xor(a, 16, 32); a += __shfl_xor(a, 8, 32);
    a += __shfl_xor(a, 4, 32);  a += __shfl_xor(a, 2, 32);
    a += __shfl_xor(a, 1, 32);
    if (e == 0) gout8[h] = 1.0f / (1.0f + expf(-(a + bg[h])));
}

// Coalesced pool: 32-lane group per channel; lanes 0..24 = window elements.
template<int C, int H, int W>
__device__ void pool_row(int b, int n, const float* fm, const float* kp,
                         const float* ms, u16* A1h, const float* wg,
                         const float* bg, float* gout, float* sx)
{
    const int t = threadIdx.x;   // 256
    const int e = t & 31, grp = t >> 5;   // 8 channel-groups
    float kx = kp[(b * NKPT + n) * 2 + 0];
    float ky = kp[(b * NKPT + n) * 2 + 1];
    int cx = (int)rintf(kx * ((float)W / 192.0f));   // RNE == jnp.round
    int cy = (int)rintf(ky * ((float)H / 256.0f));
    int dy = e / 5, dx = e % 5;
    float wgt = 0.f; int off = 0;
    if (e < 25) {
        int iy = min(max(cy + dy - 2, 0), H - 1);
        int ix = min(max(cx + dx - 2, 0), W - 1);
        off = iy * W + ix;
        wgt = expf(-(float)((dy - 2) * (dy - 2) + (dx - 2) * (dx - 2)) / 8.0f);
    }
    float ws_ = wgt;
    ws_ += __shfl_xor(ws_, 16, 32); ws_ += __shfl_xor(ws_, 8, 32);
    ws_ += __shfl_xor(ws_, 4, 32);  ws_ += __shfl_xor(ws_, 2, 32);
    ws_ += __shfl_xor(ws_, 1, 32);
    const float inv = 1.0f / ws_;

    const size_t plane = (size_t)H * W;
    const float* pf = fm + ((size_t)b * C + grp) * plane + off;
    #pragma unroll 4
    for (int c0 = grp; c0 < C; c0 += 8, pf += 8 * plane) {
        float v = 0.f;
        if (e < 25) v = wgt * (*pf);
        v += __shfl_xor(v, 16, 32); v += __shfl_xor(v, 8, 32);
        v += __shfl_xor(v, 4, 32);  v += __shfl_xor(v, 2, 32);
        v += __shfl_xor(v, 1, 32);
        if (e == 0) sx[c0] = v * inv;
    }
    __syncthreads();
    u16* rowh = A1h + (size_t)(b * NKPT + n) * (2 * C);
    for (int c = t; c < C; c += 256) {
        rowh[c] = f2h(sx[c]);
        rowh[C + c] = f2h(ms[n * C + c]);
    }
    gates_from_sx(sx, C, wg, bg, gout + (size_t)(b * NKPT + n) * 8);
}

template<int C>
__device__ void meta_row(int n, const float* ms, u16* A1h, const float* wg,
                         const float* bg, float* gout, float* sx)
{
    const int t = threadIdx.x;
    u16* rowh = A1h + (size_t)(MROW + n) * (2 * C);
    for (int c = t; c < C; c += 256) {
        float v = ms[n * C + c];
        sx[c] = v;
        rowh[c] = f2h(v);
        rowh[C + c] = 0;
    }
    __syncthreads();
    gates_from_sx(sx, C, wg, bg, gout + (size_t)(MROW + n) * 8);
}

__device__ void wtrans_tile(const TD& d, int u, float* sT)  // sT: [64][65] f32
{
    const int ntx = d.N >> 6;
    const int tk = u / ntx, tn = u % ntx;
    const int k0 = tk << 6, n0 = tn << 6;
    const int t = threadIdx.x;
    {
        int r = t >> 2, cq = (t & 3) << 4;
        const float* sp = d.src + (size_t)(k0 + r) * d.N + n0 + cq;
        #pragma unroll
        for (int i = 0; i < 4; ++i) {
            float4 v = *(const float4*)(sp + 4 * i);
            sT[r * 65 + cq + 4 * i + 0] = v.x;
            sT[r * 65 + cq + 4 * i + 1] = v.y;
            sT[r * 65 + cq + 4 * i + 2] = v.z;
            sT[r * 65 + cq + 4 * i + 3] = v.w;
        }
    }
    __syncthreads();
    {
        int nn = t >> 2, kq = (t & 3) << 4;
        u16 hv[16] __attribute__((aligned(16)));
        #pragma unroll
        for (int i = 0; i < 16; ++i) hv[i] = f2h(sT[(kq + i) * 65 + nn]);
        u16* dp = d.dst + (size_t)(n0 + nn) * d.ld + d.koff + k0 + kq;
        *reinterpret_cast<uint4*>(dp) = *reinterpret_cast<uint4*>(&hv[0]);
        *reinterpret_cast<uint4*>(dp + 8) = *reinterpret_cast<uint4*>(&hv[8]);
    }
}

__global__ __launch_bounds__(256) void k1_prep(PrepP P)
{
    __shared__ float ps[64 * 65];
    int bid = blockIdx.x;
    if (bid < 1088) {
        if (bid < 544) pool_row<512, 48, 36>(bid / NKPT, bid % NKPT, P.fm1, P.kp, P.ms1, P.A1h_1, P.wg1, P.bg1, P.gout1, ps);
        else { int r = bid - 544; pool_row<256, 96, 72>(r / NKPT, r % NKPT, P.fm0, P.kp, P.ms0, P.A1h_0, P.wg0, P.bg0, P.gout0, ps); }
    } else if (bid < 1122) {
        int u = bid - 1088;
        if (u < NKPT) meta_row<512>(u, P.ms1, P.A1h_1, P.wg1, P.bg1, P.gout1, ps);
        else          meta_row<256>(u - NKPT, P.ms0, P.A1h_0, P.wg0, P.bg0, P.gout0, ps);
    } else if (bid < 1682) {
        int u = bid - 1122, i = 0;
        while (i + 1 < 8 && u >= P.td[i + 1].blk0) ++i;
        wtrans_tile(P.td[i], u - P.td[i].blk0, ps);
    } else {
        int t = threadIdx.x;
        for (int c = t; c < 512; c += 256) P.bsum1[c] = P.b2_1[c] + P.bo_1[c];
        for (int c = t; c < 256; c += 256) P.bsum0[c] = P.b2_0[c] + P.bo_0[c];
    }
}

// ----------------------------------------------- rowops: LN+relu / attn ---
// hp: [2][MPAD][C] fp16 parts. qkvp: [2][MPAD][3C]. A4: [MPAD][2C] (h16|om).
template<int C>
__device__ void attn_row(int r, const u16* qkvp, const float* gout,
                         u16* A4, float* sred)
{
    constexpr int D = C / 8;
    constexpr int TC = 3 * C;
    const size_t PS = (size_t)MPAD * TC;
    const int t = threadIdx.x;
    const int n = r % NKPT;
    const size_t rb = (size_t)r * TC;
    const size_t mb = (size_t)(MROW + n) * TC;
    {
        int dot = t >> 3, sub = t & 7;           // 32 dots x 8 threads
        int p = dot >> 3, h = dot & 7;
        size_t qb = ((p & 2) ? mb : rb) + h * D + sub * (D / 8);
        size_t kb = ((p & 1) ? mb : rb) + C + h * D + sub * (D / 8);
        float a = 0.f;
        #pragma unroll
        for (int i = 0; i < D / 8; ++i) {
            float qv = h2f(qkvp[qb + i]) + h2f(qkvp[qb + i + PS]);
            float kv = h2f(qkvp[kb + i]) + h2f(qkvp[kb + i + PS]);
            a += qv * kv;
        }
        a += __shfl_xor(a, 4, 8); a += __shfl_xor(a, 2, 8); a += __shfl_xor(a, 1, 8);
        if (sub == 0) sred[dot] = a;
    }
    if (t >= 32 && t < 40) sred[32 + (t - 32)] = gout[(size_t)r * 8 + (t - 32)];
    else if (t >= 40 && t < 48) sred[32 + (t - 32)] = gout[(size_t)(MROW + n) * 8 + (t - 40)];
    __syncthreads();
    if (t < 8) {
        int h = t;
        float scale = (float)(1.0 / sqrt((double)D));
        float c0 = 0.f, c1 = 0.f;
        #pragma unroll
        for (int s = 0; s < 2; ++s) {
            float a0 = sred[(2 * s) * 8 + h] * scale;
            float a1 = sred[(2 * s + 1) * 8 + h] * scale;
            float mx = fmaxf(a0, a1);
            float e0 = expf(a0 - mx), e1 = expf(a1 - mx);
            float inv = 1.0f / (e0 + e1);
            float gt = sred[32 + s * 8 + h];
            c0 += e0 * inv * gt;
            c1 += e1 * inv * gt;
        }
        sred[48 + h] = 0.5f * c0;
        sred[56 + h] = 0.5f * c1;
    }
    __syncthreads();
    for (int c = t; c < C; c += 256) {
        int h = c / D;
        float v0 = h2f(qkvp[rb + 2 * C + c]) + h2f(qkvp[rb + 2 * C + c + PS]);
        float v1 = h2f(qkvp[mb + 2 * C + c]) + h2f(qkvp[mb + 2 * C + c + PS]);
        A4[(size_t)r * (2 * C) + C + c] = f2h(sred[48 + h] * v0 + sred[56 + h] * v1);
    }
}

struct RP {
    const u16 *hp1, *hp0;
    u16 *A4_1, *A4_0;
    const float *g1, *be1, *g0, *be0;
    const u16 *qkvp1, *qkvp0;
    const float *gout1, *gout0;
};
__global__ __launch_bounds__(256) void k3_rowops(RP P)
{
    __shared__ float sh[64];
    int bid = blockIdx.x;
    if (bid < 1088) {
        int lvl1 = bid < 544;
        int r = lvl1 ? bid : bid - 544;
        int C = lvl1 ? 512 : 256;
        const u16* hp = lvl1 ? P.hp1 : P.hp0;
        const size_t PSh = (size_t)MPAD * C;
        u16* A4 = (lvl1 ? P.A4_1 : P.A4_0) + (size_t)r * (2 * C);
        const float* gg = lvl1 ? P.g1 : P.g0;
        const float* bb = lvl1 ? P.be1 : P.be0;
        int t = threadIdx.x;
        int nc = C >> 8;
        float v[2] = {0.f, 0.f};
        float s1 = 0.f, s2 = 0.f;
        for (int i = 0; i < nc; ++i) {
            size_t idx = (size_t)r * C + t + (i << 8);
            float x = h2f(hp[idx]) + h2f(hp[idx + PSh]);
            v[i] = x; s1 += x; s2 += x * x;
        }
        #pragma unroll
        for (int o = 32; o > 0; o >>= 1) { s1 += __shfl_down(s1, o); s2 += __shfl_down(s2, o); }
        int lane = t & 63, wv = t >> 6;
        if (lane == 0) { sh[wv * 2] = s1; sh[wv * 2 + 1] = s2; }
        __syncthreads();
        if (t == 0) {
            float a = 0.f, b = 0.f;
            #pragma unroll
            for (int q = 0; q < 4; ++q) { a += sh[q * 2]; b += sh[q * 2 + 1]; }
            float m = a / (float)C;
            float var = b / (float)C - m * m;
            sh[8] = m; sh[9] = 1.0f / sqrtf(var + 1e-5f);
        }
        __syncthreads();
        float m = sh[8], rs = sh[9];
        for (int i = 0; i < nc; ++i) {
            int c = t + (i << 8);
            float x = (v[i] - m) * rs * gg[c] + bb[c];
            A4[c] = f2h(fmaxf(x, 0.f));
        }
    } else {
        int a = bid - 1088;
        if (a < 544) attn_row<512>(a, P.qkvp1, P.gout1, P.A4_1, sh);
        else         attn_row<256>(a - 544, P.qkvp0, P.gout0, P.A4_0, sh);
    }
}

// --------------------------------------------- fallback (round-2 kernel) --
template<int C, int H, int W>
__global__ __launch_bounds__(C) void fb_level(
    const float* __restrict__ fm, const float* __restrict__ kp,
    const float* __restrict__ ms, const float* __restrict__ w1,
    const float* __restrict__ b1, const float* __restrict__ gvec,
    const float* __restrict__ beta, const float* __restrict__ w2,
    const float* __restrict__ b2, const float* __restrict__ wqkv,
    const float* __restrict__ bqkv, const float* __restrict__ wg,
    const float* __restrict__ bg, const float* __restrict__ wo,
    const float* __restrict__ bo, float* __restrict__ out)
{
    constexpr int D = C / 8;
    constexpr int NW = C / 64;
    __shared__ float x0[C], x1[C], hbuf[C];
    __shared__ float q0[C], k0[C], v0[C], q1[C], k1[C], v1[C];
    __shared__ float om[C];
    __shared__ float gw[25];
    __shared__ float gwsum_inv;
    __shared__ float redA[NW], redB[NW];
    __shared__ float stats[2];
    __shared__ float gates[2][8];
    __shared__ float att[2][2][8];
    const int j = threadIdx.x;
    const int blk = blockIdx.x;
    const int b = blk / NKPT, n = blk % NKPT;
    if (j < 25) { int dy = j / 5 - 2, dx = j % 5 - 2; gw[j] = expf(-(float)(dy*dy+dx*dx) / 8.0f); }
    __syncthreads();
    if (j == 0) { float s = 0.f; for (int t2 = 0; t2 < 25; ++t2) s += gw[t2]; gwsum_inv = 1.0f / s; }
    float kx = kp[(b * NKPT + n) * 2 + 0];
    float ky = kp[(b * NKPT + n) * 2 + 1];
    int cx = (int)rintf(kx * ((float)W / 192.0f));
    int cy = (int)rintf(ky * ((float)H / 256.0f));
    int ix[5], iy[5];
    #pragma unroll
    for (int t2 = 0; t2 < 5; ++t2) {
        ix[t2] = min(max(cx + t2 - 2, 0), W - 1);
        iy[t2] = min(max(cy + t2 - 2, 0), H - 1);
    }
    __syncthreads();
    {
        const float* fmb = fm + ((size_t)b * C + j) * (H * W);
        float acc = 0.f;
        #pragma unroll
        for (int yy = 0; yy < 5; ++yy) {
            const float* row = fmb + iy[yy] * W;
            #pragma unroll
            for (int xx = 0; xx < 5; ++xx) acc += gw[yy * 5 + xx] * row[ix[xx]];
        }
        x0[j] = acc * gwsum_inv;
        x1[j] = ms[n * C + j];
    }
    __syncthreads();
    float hacc = b1[j];
    for (int i = 0; i < C; ++i) hacc += x0[i] * w1[i * C + j];
    for (int i = 0; i < C; ++i) hacc += x1[i] * w1[(C + i) * C + j];
    {
        float s1 = hacc, s2 = hacc * hacc;
        #pragma unroll
        for (int o = 32; o > 0; o >>= 1) { s1 += __shfl_down(s1, o); s2 += __shfl_down(s2, o); }
        int lane = j & 63, wid = j >> 6;
        if (lane == 0) { redA[wid] = s1; redB[wid] = s2; }
        __syncthreads();
        if (j == 0) {
            float t1 = 0.f, t2 = 0.f;
            for (int w = 0; w < NW; ++w) { t1 += redA[w]; t2 += redB[w]; }
            float m = t1 / (float)C, v = t2 / (float)C - m * m;
            stats[0] = m; stats[1] = 1.0f / sqrtf(v + 1e-5f);
        }
        __syncthreads();
    }
    hbuf[j] = fmaxf((hacc - stats[0]) * stats[1] * gvec[j] + beta[j], 0.f);
    __syncthreads();
    float pj = b2[j];
    for (int i = 0; i < C; ++i) pj += hbuf[i] * w2[i * C + j];
    {
        float aq0 = bqkv[j], ak0 = bqkv[C + j], av0 = bqkv[2 * C + j];
        float aq1 = aq0, ak1 = ak0, av1 = av0;
        for (int i = 0; i < C; ++i) {
            float xi0 = x0[i], xi1 = x1[i];
            const float* wr = wqkv + (size_t)i * (3 * C);
            float wq = wr[j], wk = wr[C + j], wv = wr[2 * C + j];
            aq0 += xi0 * wq; aq1 += xi1 * wq;
            ak0 += xi0 * wk; ak1 += xi1 * wk;
            av0 += xi0 * wv; av1 += xi1 * wv;
        }
        q0[j] = aq0; k0[j] = ak0; v0[j] = av0;
        q1[j] = aq1; k1[j] = ak1; v1[j] = av1;
    }
    __syncthreads();
    if (j < 16) {
        int s = j >> 3, hh = j & 7;
        const float* xs = s ? x1 : x0;
        float a = bg[hh];
        for (int i = 0; i < C; ++i) a += xs[i] * wg[i * 8 + hh];
        gates[s][hh] = 1.0f / (1.0f + expf(-a));
    }
    if (j < 32) {
        int hh = j >> 2, st = j & 3;
        const float* qs = (st & 2) ? q1 : q0;
        const float* kt = (st & 1) ? k1 : k0;
        float a = 0.f;
        for (int i = hh * D; i < (hh + 1) * D; ++i) a += qs[i] * kt[i];
        att[(st >> 1)][st & 1][hh] = a;
    }
    __syncthreads();
    if (j < 16) {
        int s = j >> 3, hh = j & 7;
        const float inv = 1.0f / sqrtf((float)D);
        float a0 = att[s][0][hh] * inv, a1 = att[s][1][hh] * inv;
        float mx = fmaxf(a0, a1);
        float e0 = expf(a0 - mx), e1 = expf(a1 - mx);
        float den = e0 + e1;
        att[s][0][hh] = e0 / den; att[s][1][hh] = e1 / den;
    }
    __syncthreads();
    {
        int hh = j / D;
        float o0 = (att[0][0][hh] * v0[j] + att[0][1][hh] * v1[j]) * gates[0][hh];
        float o1 = (att[1][0][hh] * v0[j] + att[1][1][hh] * v1[j]) * gates[1][hh];
        om[j] = 0.5f * (o0 + o1);
    }
    __syncthreads();
    float oacc = bo[j];
    for (int i = 0; i < C; ++i) oacc += om[i] * wo[i * C + j];
    out[((size_t)b * NKPT + n) * C + j] = oacc + pj;
}

// ------------------------------------------------------------- launch -----
extern "C" void kernel_launch(void* const* d_in, const int* in_sizes, int n_in,
                              void* d_out, int out_size, void* d_ws, size_t ws_size,
                              hipStream_t stream) {
    (void)in_sizes; (void)n_in; (void)out_size;
    const float* fm0  = (const float*)d_in[0];
    const float* fm1  = (const float*)d_in[1];
    const float* kp   = (const float*)d_in[2];
    const float* ms0     = (const float*)d_in[3];
    const float* p0_w1   = (const float*)d_in[4];
    const float* p0_b1   = (const float*)d_in[5];
    const float* p0_g    = (const float*)d_in[6];
    const float* p0_beta = (const float*)d_in[7];
    const float* p0_w2   = (const float*)d_in[8];
    const float* p0_b2   = (const float*)d_in[9];
    const float* a0_wqkv = (const float*)d_in[10];
    const float* a0_bqkv = (const float*)d_in[11];
    const float* a0_wg   = (const float*)d_in[12];
    const float* a0_bg   = (const float*)d_in[13];
    const float* a0_wo   = (const float*)d_in[14];
    const float* a0_bo   = (const float*)d_in[15];
    const float* ms1     = (const float*)d_in[16];
    const float* p1_w1   = (const float*)d_in[17];
    const float* p1_b1   = (const float*)d_in[18];
    const float* p1_g    = (const float*)d_in[19];
    const float* p1_beta = (const float*)d_in[20];
    const float* p1_w2   = (const float*)d_in[21];
    const float* p1_b2   = (const float*)d_in[22];
    const float* a1_wqkv = (const float*)d_in[23];
    const float* a1_bqkv = (const float*)d_in[24];
    const float* a1_wg   = (const float*)d_in[25];
    const float* a1_bg   = (const float*)d_in[26];
    const float* a1_wo   = (const float*)d_in[27];
    const float* a1_bo   = (const float*)d_in[28];

    float* out0 = (float*)d_out;                               // (544,256)
    float* out1 = (float*)d_out + (size_t)MROW * 256;          // (544,512)

    const size_t WS_NEED = 15400000;
    if (ws_size < WS_NEED || d_ws == nullptr) {
        fb_level<256, 96, 72><<<MROW, 256, 0, stream>>>(
            fm0, kp, ms0, p0_w1, p0_b1, p0_g, p0_beta, p0_w2, p0_b2,
            a0_wqkv, a0_bqkv, a0_wg, a0_bg, a0_wo, a0_bo, out0);
        fb_level<512, 48, 36><<<MROW, 512, 0, stream>>>(
            fm1, kp, ms1, p1_w1, p1_b1, p1_g, p1_beta, p1_w2, p1_b2,
            a1_wqkv, a1_bqkv, a1_wg, a1_bg, a1_wo, a1_bo, out1);
        return;
    }

    char* cur = (char*)d_ws;
    auto alloc = [&](size_t bytes) { char* p = cur; cur += (bytes + 255) & ~(size_t)255; return p; };
    u16* A1h_1 = (u16*)alloc((size_t)MPAD * 1024 * 2);
    u16* A1h_0 = (u16*)alloc((size_t)MPAD * 512 * 2);
    u16* hp_1  = (u16*)alloc((size_t)2 * MPAD * 512 * 2);   // [2][MPAD][512]
    u16* hp_0  = (u16*)alloc((size_t)2 * MPAD * 256 * 2);
    u16* qkvp_1 = (u16*)alloc((size_t)2 * MPAD * 1536 * 2); // [2][MPAD][1536]
    u16* qkvp_0 = (u16*)alloc((size_t)2 * MPAD * 768 * 2);
    u16* A4_1  = (u16*)alloc((size_t)MPAD * 1024 * 2);      // [MPAD][h16|om]
    u16* A4_0  = (u16*)alloc((size_t)MPAD * 512 * 2);
    u16* w1T_1   = (u16*)alloc((size_t)512 * 1024 * 2);
    u16* wqkvT_1 = (u16*)alloc((size_t)1536 * 512 * 2);
    u16* w24T_1  = (u16*)alloc((size_t)512 * 1024 * 2);     // [512][w2T|woT]
    u16* w1T_0   = (u16*)alloc((size_t)256 * 512 * 2);
    u16* wqkvT_0 = (u16*)alloc((size_t)768 * 256 * 2);
    u16* w24T_0  = (u16*)alloc((size_t)256 * 512 * 2);
    float* gout1 = (float*)alloc((size_t)(MROW + NKPT) * 8 * 4);
    float* gout0 = (float*)alloc((size_t)(MROW + NKPT) * 8 * 4);
    float* bsum1 = (float*)alloc(512 * 4);
    float* bsum0 = (float*)alloc(256 * 4);

    // ---- K1: pool(+gates) + meta + weight transpose/pack + bias-sum ----
    PrepP pp;
    pp.fm0 = fm0; pp.fm1 = fm1; pp.kp = kp; pp.ms0 = ms0; pp.ms1 = ms1;
    pp.wg0 = a0_wg; pp.bg0 = a0_bg; pp.wg1 = a1_wg; pp.bg1 = a1_bg;
    pp.b2_1 = p1_b2; pp.bo_1 = a1_bo; pp.b2_0 = p0_b2; pp.bo_0 = a0_bo;
    pp.A1h_0 = A1h_0; pp.A1h_1 = A1h_1;
    pp.gout0 = gout0; pp.gout1 = gout1;
    pp.bsum1 = bsum1; pp.bsum0 = bsum0;
    int tcum = 0;
    auto setTD = [&](int i, const float* src, u16* dst, int K, int N, int ld, int koff) {
        pp.td[i].src = src; pp.td[i].dst = dst; pp.td[i].K = K; pp.td[i].N = N;
        pp.td[i].ld = ld; pp.td[i].koff = koff;
        pp.td[i].blk0 = tcum; tcum += (K / 64) * (N / 64);
    };
    setTD(0, p1_w1,   w1T_1,   1024, 512,  1024, 0);
    setTD(1, a1_wqkv, wqkvT_1, 512,  1536, 512,  0);
    setTD(2, p1_w2,   w24T_1,  512,  512,  1024, 0);
    setTD(3, a1_wo,   w24T_1,  512,  512,  1024, 512);
    setTD(4, p0_w1,   w1T_0,   512,  256,  512,  0);
    setTD(5, a0_wqkv, wqkvT_0, 256,  768,  256,  0);
    setTD(6, p0_w2,   w24T_0,  256,  256,  512,  0);
    setTD(7, a0_wo,   w24T_0,  256,  256,  512,  256);
    k1_prep<<<1683, 256, 0, stream>>>(pp);   // 1088 + 34 + 560 + 1

    // ---- K2: w1 + wqkv GEMMs, split-K=2 -> fp16 part buffers (no atomics) --
    GPp g2; g2.nd = 4;
    g2.d[0] = { A1h_1, w1T_1,   p1_b1,   hp_1,   1024, 512,  1024, 512,  8,  2 };
    g2.d[1] = { A1h_1, wqkvT_1, a1_bqkv, qkvp_1, 1024, 1536, 512,  1536, 24, 2 };
    g2.d[2] = { A1h_0, w1T_0,   p0_b1,   hp_0,   512,  256,  512,  256,  4,  2 };
    g2.d[3] = { A1h_0, wqkvT_0, a0_bqkv, qkvp_0, 512,  768,  256,  768,  12, 2 };
    g2.blk0[0] = 0;
    for (int i = 0; i < 4; ++i) g2.blk0[i + 1] = g2.blk0[i] + 9 * g2.d[i].ntiles * g2.d[i].sk;
    gemm_part<<<g2.blk0[4], 256, 0, stream>>>(g2);

    // ---- K3: LN+relu -> A4 left  ||  attention -> A4 right ----
    RP rp;
    rp.hp1 = hp_1; rp.hp0 = hp_0; rp.A4_1 = A4_1; rp.A4_0 = A4_0;
    rp.g1 = p1_g; rp.be1 = p1_beta; rp.g0 = p0_g; rp.be0 = p0_beta;
    rp.qkvp1 = qkvp_1; rp.qkvp0 = qkvp_0;
    rp.gout1 = gout1; rp.gout0 = gout0;
    k3_rowops<<<2176, 256, 0, stream>>>(rp);

    // ---- K4: out = [h16|om] @ [w2T|woT]^T + (b2+bo), direct store ----
    GPo g4; g4.nd = 2;
    g4.d[0] = { A4_1, w24T_1, bsum1, out1, 1024, 512, 1024, 512, MROW, 8 };
    g4.d[1] = { A4_0, w24T_0, bsum0, out0, 512,  256, 512,  256, MROW, 4 };
    g4.blk0[0] = 0;
    for (int i = 0; i < 2; ++i) g4.blk0[i + 1] = g4.blk0[i] + 18 * g4.d[i].ntiles;
    gemm_out<<<g4.blk0[2], 256, 0, stream>>>(g4);
}